// Round 15
// baseline (280.096 us; speedup 1.0000x reference)
//
#include <hip/hip_runtime.h>
#include <hip/hip_bf16.h>
#include <math.h>

#define NEG_SLOPE 0.2f

// CSR binning parameters (N=100000, E+N~1.7M; requires N < 2^18 and NB <= 256)
#define NPB 512       // nodes per bucket
#define NPB_SH 9
#define SRC_BITS 18
#define LCAP 16384    // LDS adj staging capacity (edges) per bucket
#define BCAP 16384    // fixed per-bucket record capacity (filtered mean ~2.4K)

typedef __attribute__((ext_vector_type(8))) short short8;
typedef __attribute__((ext_vector_type(4))) float f32x4;

__device__ __forceinline__ float leaky(float x) { return x > 0.f ? x : NEG_SLOPE * x; }

__device__ __forceinline__ unsigned short f2bf(float f) {
  unsigned u = __float_as_uint(f);
  unsigned r = (u + 0x7FFFu + ((u >> 16) & 1u)) >> 16;  // RNE
  return (unsigned short)r;
}

// LDS-only barrier: orders ds_read/ds_write across waves WITHOUT draining
// outstanding global loads/stores (T4: prefetch stays in flight across tiles).
#define LGKM_BARRIER()                                   \
  do {                                                   \
    asm volatile("s_waitcnt lgkmcnt(0)" ::: "memory");   \
    __builtin_amdgcn_s_barrier();                        \
  } while (0)

// ---------------- GAT layer 1 linear: h1[N,128] = x[N,64] @ W1[64,128] (bf16 out)
__global__ void k_h1(const float* __restrict__ x, const float* __restrict__ W1,
                     const float* __restrict__ att_src, const float* __restrict__ att_dst,
                     unsigned short* __restrict__ h1, float* __restrict__ a_s,
                     float* __restrict__ a_d, int N) {
  __shared__ __align__(16) float W1s[64 * 128];   // 32 KB
  __shared__ __align__(16) float xs[32][64];      // 8 KB
  const int tid = threadIdx.x;
  for (int i = tid; i < 64 * 128; i += 256) W1s[i] = W1[i];
  const int node0 = blockIdx.x * 32;
  for (int i = tid; i < 512; i += 256) {
    const int nn = node0 + (i >> 4);
    if (nn < N) ((float4*)xs)[i] = *(const float4*)(x + (size_t)nn * 64 + (i & 15) * 4);
  }
  const int ln  = tid >> 7;   // node slot 0/1
  const int col = tid & 127;  // output channel
  const int head = col >> 6;
  const int c = col & 63;
  const float as_w = att_src[head * 64 + c];
  const float ad_w = att_dst[head * 64 + c];
  __syncthreads();  // W1s + xs ready
  float wreg[64];
#pragma unroll
  for (int cc = 0; cc < 64; ++cc) wreg[cc] = W1s[cc * 128 + col];

  for (int it = 0; it < 16; ++it) {
    const int slot = it * 2 + ln;
    const int n = node0 + slot;
    if (n >= N) continue;
    float acc = 0.f;
#pragma unroll
    for (int q = 0; q < 16; ++q) {
      const float4 xv = *(const float4*)&xs[slot][q * 4];
      acc = fmaf(xv.x, wreg[q * 4 + 0], acc);
      acc = fmaf(xv.y, wreg[q * 4 + 1], acc);
      acc = fmaf(xv.z, wreg[q * 4 + 2], acc);
      acc = fmaf(xv.w, wreg[q * 4 + 3], acc);
    }
    h1[(size_t)n * 128 + col] = f2bf(acc);
    float vs = acc * as_w;
    float vd = acc * ad_w;
#pragma unroll
    for (int off = 32; off > 0; off >>= 1) {
      vs += __shfl_down(vs, off, 64);
      vd += __shfl_down(vd, off, 64);
    }
    if (c == 0) { a_s[n * 2 + head] = vs; a_d[n * 2 + head] = vd; }
  }
}

// ---------------- combined init: bucket cursors + frontier flags + counters ----------
__global__ void k_init(int* __restrict__ cursor, int NB, int* __restrict__ flagC,
                       int* __restrict__ flag1, int* __restrict__ cnt, int N) {
  const int i = blockIdx.x * 256 + threadIdx.x;
  if (i < NB) cursor[i] = i * BCAP;
  if (i < N) { flagC[i] = 0; flag1[i] = 0; }
  if (i < 2) cnt[i] = 0;
}

// ---------------- demand-driven frontier: plain-store marking (no atomics) ----------
__global__ void k_markC(const int* __restrict__ ctx, int nctx, int* __restrict__ flagC,
                        int* __restrict__ flag1) {
  const int i = blockIdx.x * 256 + threadIdx.x;
  if (i >= nctx) return;
  const int n = ctx[i];
  flagC[n] = 1;   // idempotent
  flag1[n] = 1;
}

// edge-scan: flag1 |= {src[e] : dst[e] ∈ C}. Plain stores, fire-and-forget.
__global__ void k_markS1e(const int* __restrict__ src, const int* __restrict__ dst,
                          int E, int Etot, const int* __restrict__ flagC,
                          int* __restrict__ flag1) {
  const int e = blockIdx.x * 256 + threadIdx.x;
  if (e >= Etot) return;
  int s, d;
  if (e < E) { s = src[e]; d = dst[e]; } else { s = d = e - E; }
  if (flagC[d]) flag1[s] = 1;
}

// compaction: flags -> lists. One global atomicAdd per block per list.
__global__ void k_compact(const int* __restrict__ flagC, const int* __restrict__ flag1,
                          int* __restrict__ listC, int* __restrict__ list1,
                          int* __restrict__ cnt, int N) {
  __shared__ int lc, l1, bc, b1;
  const int i = blockIdx.x * 256 + threadIdx.x;
  if (threadIdx.x == 0) { lc = 0; l1 = 0; }
  __syncthreads();
  int pc = -1, p1 = -1;
  if (i < N) {
    if (flagC[i]) pc = atomicAdd(&lc, 1);
    if (flag1[i]) p1 = atomicAdd(&l1, 1);
  }
  __syncthreads();
  if (threadIdx.x == 0) {
    bc = lc ? atomicAdd(&cnt[0], lc) : 0;
    b1 = l1 ? atomicAdd(&cnt[1], l1) : 0;
  }
  __syncthreads();
  if (pc >= 0) listC[bc + pc] = i;
  if (p1 >= 0) list1[b1 + p1] = i;
}

// ---------------- CSR build, FILTERED to rows in S1 (flag1[dst]) ----------------
__global__ __launch_bounds__(1024) void k_bscatter(const int* __restrict__ src,
                                                   const int* __restrict__ dst, int E, int Etot,
                                                   int epb, const int* __restrict__ flag1,
                                                   int* __restrict__ cursor,
                                                   unsigned* __restrict__ rec, int NB) {
  __shared__ int hist[256];
  __shared__ int cur[256];
  const int tid = threadIdx.x;
  if (tid < 256) hist[tid] = 0;
  __syncthreads();
  const int e0 = blockIdx.x * epb;
  const int e1 = min(e0 + epb, Etot);
  for (int e = e0 + tid; e < e1; e += 1024) {
    const int d = (e < E) ? dst[e] : (e - E);
    if (flag1[d]) atomicAdd(&hist[d >> NPB_SH], 1);
  }
  __syncthreads();
  if (tid < NB) {
    const int c = hist[tid];
    cur[tid] = c ? atomicAdd(&cursor[tid], c) : 0;
  }
  __syncthreads();
  for (int e = e0 + tid; e < e1; e += 1024) {
    int sv, d;
    if (e < E) { sv = src[e]; d = dst[e]; } else { sv = d = e - E; }
    if (!flag1[d]) continue;
    const int b = d >> NPB_SH;
    const int p = atomicAdd(&cur[b], 1);
    rec[p] = (unsigned)sv | ((unsigned)(d & (NPB - 1)) << SRC_BITS);
  }
}

// scan bucket counts (cursor deltas) -> bucketBase; rowptr[N] = filtered total
__global__ void k_bscan2(const int* __restrict__ cursor, int* __restrict__ bucketBase,
                         int NB, int* __restrict__ rowptr, int N) {
  __shared__ int s[256];
  const int tid = threadIdx.x;
  const int v = (tid < NB) ? (cursor[tid] - tid * BCAP) : 0;
  s[tid] = v;
  __syncthreads();
  for (int off = 1; off < 256; off <<= 1) {
    const int t = (tid >= off) ? s[tid - off] : 0;
    __syncthreads();
    s[tid] += t;
    __syncthreads();
  }
  if (tid < NB) bucketBase[tid] = s[tid] - v;
  if (tid == 0) { bucketBase[NB] = s[255]; rowptr[N] = s[255]; }
}

__global__ __launch_bounds__(1024) void k_bcsr(const unsigned* __restrict__ rec,
                                               const int* __restrict__ bucketBase,
                                               int* __restrict__ rowptr, int* __restrict__ adj,
                                               int N, int NB) {
  __shared__ int ldeg[NPB];
  __shared__ int s[NPB];
  __shared__ int ladj[LCAP];
  const int b = blockIdx.x;
  const int tid = threadIdx.x;
  const int o0 = bucketBase[b];
  const int cnt = bucketBase[b + 1] - o0;
  const int r0 = b * BCAP;
  if (tid < NPB) ldeg[tid] = 0;
  __syncthreads();
  for (int i = tid; i < cnt; i += 1024)
    atomicAdd(&ldeg[rec[r0 + i] >> SRC_BITS], 1);
  __syncthreads();
  int v = 0;
  if (tid < NPB) { v = ldeg[tid]; s[tid] = v; }
  __syncthreads();
  for (int off = 1; off < NPB; off <<= 1) {
    int t = 0;
    if (tid < NPB && tid >= off) t = s[tid - off];
    __syncthreads();
    if (tid < NPB) s[tid] += t;
    __syncthreads();
  }
  if (tid < NPB) {
    const int excl = s[tid] - v;
    const int node = b * NPB + tid;
    if (node < N) rowptr[node] = o0 + excl;
    ldeg[tid] = excl;  // reuse as scatter cursor
  }
  __syncthreads();
  if (cnt <= LCAP) {
    for (int i = tid; i < cnt; i += 1024) {
      const unsigned r = rec[r0 + i];
      const int p = atomicAdd(&ldeg[r >> SRC_BITS], 1);
      ladj[p] = (int)(r & ((1u << SRC_BITS) - 1));
    }
    __syncthreads();
    for (int i = tid; i < cnt; i += 1024) adj[o0 + i] = ladj[i];
  } else {  // safety fallback (never expected)
    for (int i = tid; i < cnt; i += 1024) {
      const unsigned r = rec[r0 + i];
      const int p = atomicAdd(&ldeg[r >> SRC_BITS], 1);
      adj[o0 + p] = (int)(r & ((1u << SRC_BITS) - 1));
    }
  }
}

// ---------------- GAT layer 1 aggregate over list1 (x4 unroll) -------
__global__ void k_gat1(const unsigned short* __restrict__ h1, const float* __restrict__ as1,
                       const float* __restrict__ ad1, const int* __restrict__ rowptr,
                       const int* __restrict__ adj, const float* __restrict__ b1,
                       float* __restrict__ g, const int* __restrict__ list1,
                       const int* __restrict__ cnt) {
  const int w = threadIdx.x >> 6;
  const int l = threadIdx.x & 63;
  const int idx = blockIdx.x * 4 + w;
  if (idx >= cnt[1]) return;
  const int n = list1[idx];
  const int half = l >> 5;
  const int q = l & 31;       // channels 4q..4q+3
  const int head = q >> 4;
  const float adh = ad1[n * 2 + head];
  float a0 = 0.f, a1 = 0.f, a2 = 0.f, a3 = 0.f, dsum = 0.f;
  const int kb = rowptr[n], ke = rowptr[n + 1];
  const int kend = ke - 1;
  for (int k = kb + half; k < ke; k += 8) {
    const int e1 = k + 2, e2 = k + 4, e3 = k + 6;
    const int s0 = adj[k];
    const int s1 = adj[min(e1, kend)];
    const int s2 = adj[min(e2, kend)];
    const int s3 = adj[min(e3, kend)];
    const float x0 = as1[s0 * 2 + head] + adh;
    const float x1 = as1[s1 * 2 + head] + adh;
    const float x2 = as1[s2 * 2 + head] + adh;
    const float x3 = as1[s3 * 2 + head] + adh;
    const uint2 u0 = *(const uint2*)(h1 + (size_t)s0 * 128 + 4 * q);
    const uint2 u1 = *(const uint2*)(h1 + (size_t)s1 * 128 + 4 * q);
    const uint2 u2 = *(const uint2*)(h1 + (size_t)s2 * 128 + 4 * q);
    const uint2 u3 = *(const uint2*)(h1 + (size_t)s3 * 128 + 4 * q);
    const float w0 = __expf(leaky(x0));
    const float w1 = (e1 < ke) ? __expf(leaky(x1)) : 0.f;
    const float w2 = (e2 < ke) ? __expf(leaky(x2)) : 0.f;
    const float w3 = (e3 < ke) ? __expf(leaky(x3)) : 0.f;
    dsum += (w0 + w1) + (w2 + w3);
    a0 = fmaf(w0, __uint_as_float(u0.x << 16), a0);
    a1 = fmaf(w0, __uint_as_float(u0.x & 0xFFFF0000u), a1);
    a2 = fmaf(w0, __uint_as_float(u0.y << 16), a2);
    a3 = fmaf(w0, __uint_as_float(u0.y & 0xFFFF0000u), a3);
    a0 = fmaf(w1, __uint_as_float(u1.x << 16), a0);
    a1 = fmaf(w1, __uint_as_float(u1.x & 0xFFFF0000u), a1);
    a2 = fmaf(w1, __uint_as_float(u1.y << 16), a2);
    a3 = fmaf(w1, __uint_as_float(u1.y & 0xFFFF0000u), a3);
    a0 = fmaf(w2, __uint_as_float(u2.x << 16), a0);
    a1 = fmaf(w2, __uint_as_float(u2.x & 0xFFFF0000u), a1);
    a2 = fmaf(w2, __uint_as_float(u2.y << 16), a2);
    a3 = fmaf(w2, __uint_as_float(u2.y & 0xFFFF0000u), a3);
    a0 = fmaf(w3, __uint_as_float(u3.x << 16), a0);
    a1 = fmaf(w3, __uint_as_float(u3.x & 0xFFFF0000u), a1);
    a2 = fmaf(w3, __uint_as_float(u3.y << 16), a2);
    a3 = fmaf(w3, __uint_as_float(u3.y & 0xFFFF0000u), a3);
  }
  a0 += __shfl_xor(a0, 32, 64);
  a1 += __shfl_xor(a1, 32, 64);
  a2 += __shfl_xor(a2, 32, 64);
  a3 += __shfl_xor(a3, 32, 64);
  dsum += __shfl_xor(dsum, 32, 64);
  if (half == 0) {
    const float inv = 1.f / (dsum + 1e-16f);
    const float4 bv = *(const float4*)(b1 + 4 * q);
    float g0 = fmaf(a0, inv, bv.x);
    float g1 = fmaf(a1, inv, bv.y);
    float g2v = fmaf(a2, inv, bv.z);
    float g3 = fmaf(a3, inv, bv.w);
    g0 = g0 > 0.f ? g0 : expm1f(g0);
    g1 = g1 > 0.f ? g1 : expm1f(g1);
    g2v = g2v > 0.f ? g2v : expm1f(g2v);
    g3 = g3 > 0.f ? g3 : expm1f(g3);
    *(float4*)(g + (size_t)n * 128 + 4 * q) = make_float4(g0, g1, g2v, g3);
  }
}

// ---------------- GAT layer 2 linear over list1: h2 = g @ W2 (bf16 out)
__global__ void k_h2(const float* __restrict__ g, const float* __restrict__ W2,
                     const float* __restrict__ att_s, const float* __restrict__ att_d,
                     unsigned short* __restrict__ h2, float* __restrict__ a_s,
                     float* __restrict__ a_d, const int* __restrict__ list1,
                     const int* __restrict__ cnt) {
  const int cnt1 = cnt[1];
  const int base0 = blockIdx.x * 32;
  if (base0 >= cnt1) return;
  __shared__ __align__(16) float W2s[128 * 64];
  __shared__ __align__(16) float gs[2][128];
  __shared__ float part[2][64];
  for (int i = threadIdx.x; i < 128 * 64; i += 256) W2s[i] = W2[i];
  const int col = threadIdx.x & 63;
  const int kh  = (threadIdx.x >> 6) & 1;
  const int ln  = threadIdx.x >> 7;
  const float as_w = att_s[col], ad_w = att_d[col];
  __syncthreads();
  float wreg[64];
#pragma unroll
  for (int cc = 0; cc < 64; ++cc) wreg[cc] = W2s[(kh * 64 + cc) * 64 + col];

  for (int it = 0; it < 16; ++it) {
    const int sbase = base0 + it * 2;
    __syncthreads();
    {
      const int slot = sbase + (threadIdx.x >> 7);
      if (slot < cnt1) {
        const int nn = list1[slot];
        gs[threadIdx.x >> 7][threadIdx.x & 127] = g[(size_t)nn * 128 + (threadIdx.x & 127)];
      }
    }
    __syncthreads();
    const int slot = sbase + ln;
    const int n = (slot < cnt1) ? list1[slot] : -1;
    float acc = 0.f;
    if (n >= 0) {
#pragma unroll
      for (int q = 0; q < 16; ++q) {
        const float4 gv = *(const float4*)&gs[ln][kh * 64 + q * 4];
        acc = fmaf(gv.x, wreg[q * 4 + 0], acc);
        acc = fmaf(gv.y, wreg[q * 4 + 1], acc);
        acc = fmaf(gv.z, wreg[q * 4 + 2], acc);
        acc = fmaf(gv.w, wreg[q * 4 + 3], acc);
      }
    }
    if (kh == 1) part[ln][col] = acc;
    __syncthreads();
    if (kh == 0 && n >= 0) {
      acc += part[ln][col];
      h2[(size_t)n * 64 + col] = f2bf(acc);
      float vs = acc * as_w, vd = acc * ad_w;
#pragma unroll
      for (int off = 32; off > 0; off >>= 1) {
        vs += __shfl_down(vs, off, 64);
        vd += __shfl_down(vd, off, 64);
      }
      if (col == 0) { a_s[n] = vs; a_d[n] = vd; }
    }
  }
}

// ---------------- GAT layer 2 aggregate over listC (x4 unroll) ----------------
__global__ void k_gat2(const unsigned short* __restrict__ h2, const float* __restrict__ as2,
                       const float* __restrict__ ad2, const int* __restrict__ rowptr,
                       const int* __restrict__ adj, const float* __restrict__ b2,
                       float* __restrict__ g2, const int* __restrict__ listC,
                       const int* __restrict__ cnt) {
  const int w = threadIdx.x >> 6;
  const int l = threadIdx.x & 63;
  const int idx = blockIdx.x * 4 + w;
  if (idx >= cnt[0]) return;
  const int n = listC[idx];
  const int half = l >> 5;
  const int q = l & 31;       // channels 2q, 2q+1
  const float adh = ad2[n];
  float a0 = 0.f, a1 = 0.f, dsum = 0.f;
  const int kb = rowptr[n], ke = rowptr[n + 1];
  const int kend = ke - 1;
  for (int k = kb + half; k < ke; k += 8) {
    const int e1 = k + 2, e2 = k + 4, e3 = k + 6;
    const int s0 = adj[k];
    const int s1 = adj[min(e1, kend)];
    const int s2 = adj[min(e2, kend)];
    const int s3 = adj[min(e3, kend)];
    const float x0 = as2[s0] + adh;
    const float x1 = as2[s1] + adh;
    const float x2 = as2[s2] + adh;
    const float x3 = as2[s3] + adh;
    const unsigned u0 = *(const unsigned*)(h2 + (size_t)s0 * 64 + 2 * q);
    const unsigned u1 = *(const unsigned*)(h2 + (size_t)s1 * 64 + 2 * q);
    const unsigned u2 = *(const unsigned*)(h2 + (size_t)s2 * 64 + 2 * q);
    const unsigned u3 = *(const unsigned*)(h2 + (size_t)s3 * 64 + 2 * q);
    const float w0 = __expf(leaky(x0));
    const float w1 = (e1 < ke) ? __expf(leaky(x1)) : 0.f;
    const float w2 = (e2 < ke) ? __expf(leaky(x2)) : 0.f;
    const float w3 = (e3 < ke) ? __expf(leaky(x3)) : 0.f;
    dsum += (w0 + w1) + (w2 + w3);
    a0 = fmaf(w0, __uint_as_float(u0 << 16), a0);
    a1 = fmaf(w0, __uint_as_float(u0 & 0xFFFF0000u), a1);
    a0 = fmaf(w1, __uint_as_float(u1 << 16), a0);
    a1 = fmaf(w1, __uint_as_float(u1 & 0xFFFF0000u), a1);
    a0 = fmaf(w2, __uint_as_float(u2 << 16), a0);
    a1 = fmaf(w2, __uint_as_float(u2 & 0xFFFF0000u), a1);
    a0 = fmaf(w3, __uint_as_float(u3 << 16), a0);
    a1 = fmaf(w3, __uint_as_float(u3 & 0xFFFF0000u), a1);
  }
  a0 += __shfl_xor(a0, 32, 64);
  a1 += __shfl_xor(a1, 32, 64);
  dsum += __shfl_xor(dsum, 32, 64);
  if (half == 0) {
    const float inv = 1.f / (dsum + 1e-16f);
    const float2 bv = *(const float2*)(b2 + 2 * q);
    ((float2*)g2)[(size_t)n * 32 + q] =
        make_float2(fmaf(a0, inv, bv.x), fmaf(a1, inv, bv.y));
  }
}

// ---------------- build x matrix, bf16, K-blocked: xb[k/32][512][32] ----------------
__global__ void k_xmat(const int* __restrict__ user_idx, const int* __restrict__ ctx_idx,
                       const float* __restrict__ user_emb, const float* __restrict__ g2,
                       unsigned short* __restrict__ xb) {
  const int b = blockIdx.x;
  const int k = threadIdx.x;  // 0..255
  float v;
  if (k < 64) {
    v = user_emb[(size_t)user_idx[b] * 64 + k];
  } else {
    const int c = (k - 64) >> 6;
    v = g2[(size_t)ctx_idx[b * 3 + c] * 64 + (k & 63)];
  }
  xb[(size_t)(k >> 5) * (512 * 32) + b * 32 + (k & 31)] = f2bf(v);
}

// ---------------- final FC via MFMA, A-persistent, dbuf LDS, lgkm-only barriers ----
__global__ __launch_bounds__(512) void k_fc(const unsigned short* __restrict__ xb,
                                            const float* __restrict__ fc_w,
                                            const float* __restrict__ fc_b,
                                            float* __restrict__ out, int NSRV,
                                            int ntiles, int gstride) {
  __shared__ __align__(16) unsigned short Blds[2][32 * 264];  // 33 KB

  const int tid = threadIdx.x;
  const int w = tid >> 6;
  const int lane = tid & 63;
  const int l15 = lane & 15;
  const int kg = lane >> 4;

  if (blockIdx.x >= (unsigned)ntiles) return;

  // persistent A fragments (serve as the MFMA *B* operand after the swap)
  short8 afr[4][8];
#pragma unroll
  for (int mf = 0; mf < 4; ++mf) {
    const int row = w * 64 + mf * 16 + l15;
#pragma unroll
    for (int ks = 0; ks < 8; ++ks) {
      afr[mf][ks] = *(const short8*)(xb + (size_t)ks * 16384 + row * 32 + kg * 8);
    }
  }

  const int sc = tid & 31;   // stage: col in tile
  const int sk = tid >> 5;   // stage: k row 0..15

  float v[16];
  auto loadv = [&](int t) {
    const int cg = t * 32 + sc;
    const bool okc = cg < NSRV;
#pragma unroll
    for (int i = 0; i < 16; ++i)
      v[i] = okc ? __builtin_nontemporal_load(fc_w + (size_t)(sk + i * 16) * NSRV + cg) : 0.f;
  };
  auto writev = [&](int buf) {
#pragma unroll
    for (int i = 0; i < 16; ++i)
      Blds[buf][sc * 264 + sk + i * 16] = f2bf(v[i]);
  };

  // prologue: tile t0 staged, loads for t0+gs in flight
  loadv(blockIdx.x);
  writev(0);
  if (blockIdx.x + gstride < ntiles) loadv(blockIdx.x + gstride);
  LGKM_BARRIER();

  int cur = 0;
  for (int t = blockIdx.x; t < ntiles; t += gstride) {
    if (t + gstride < ntiles) writev(cur ^ 1);   // vmcnt dep on loads issued a tile ago
    if (t + 2 * gstride < ntiles) loadv(t + 2 * gstride);  // stays in flight across barrier
    const int j0 = t * 32;
#pragma unroll
    for (int nf = 0; nf < 2; ++nf) {
      short8 bfr[8];
#pragma unroll
      for (int ks = 0; ks < 8; ++ks)
        bfr[ks] = *(const short8*)&Blds[cur][(nf * 16 + l15) * 264 + ks * 32 + kg * 8];
      f32x4 acc[4];
#pragma unroll
      for (int mf = 0; mf < 4; ++mf) acc[mf] = (f32x4){0.f, 0.f, 0.f, 0.f};
#pragma unroll
      for (int ks = 0; ks < 8; ++ks)
#pragma unroll
        for (int mf = 0; mf < 4; ++mf)
          acc[mf] = __builtin_amdgcn_mfma_f32_16x16x32_bf16(bfr[ks], afr[mf][ks], acc[mf], 0, 0, 0);
      const int jc = j0 + nf * 16 + kg * 4;
      if (j0 + 32 <= NSRV) {
        const float4 bias = *(const float4*)(fc_b + jc);
#pragma unroll
        for (int mf = 0; mf < 4; ++mf) {
          const int row = w * 64 + mf * 16 + l15;
          f32x4 o;
          o[0] = acc[mf][0] + bias.x;
          o[1] = acc[mf][1] + bias.y;
          o[2] = acc[mf][2] + bias.z;
          o[3] = acc[mf][3] + bias.w;
          __builtin_nontemporal_store(o, (f32x4*)(out + (size_t)row * NSRV + jc));
        }
      } else {
#pragma unroll
        for (int mf = 0; mf < 4; ++mf) {
          const int row = w * 64 + mf * 16 + l15;
#pragma unroll
          for (int r = 0; r < 4; ++r) {
            const int j = jc + r;
            if (j < NSRV) out[(size_t)row * NSRV + j] = acc[mf][r] + fc_b[j];
          }
        }
      }
    }
    LGKM_BARRIER();  // orders LDS only; prefetch loads + output stores stay in flight
    cur ^= 1;
  }
}

// =====================================================================
extern "C" void kernel_launch(void* const* d_in, const int* in_sizes, int n_in,
                              void* d_out, int out_size, void* d_ws, size_t ws_size,
                              hipStream_t stream) {
  const int* user_idx    = (const int*)d_in[0];
  const int* context_idx = (const int*)d_in[1];
  const int* edge_index  = (const int*)d_in[2];
  const float* user_emb  = (const float*)d_in[3];
  const float* service_emb = (const float*)d_in[4];
  const float* W1        = (const float*)d_in[5];
  const float* att_src1  = (const float*)d_in[6];
  const float* att_dst1  = (const float*)d_in[7];
  const float* b1        = (const float*)d_in[8];
  const float* W2        = (const float*)d_in[9];
  const float* att_src2  = (const float*)d_in[10];
  const float* att_dst2  = (const float*)d_in[11];
  const float* b2        = (const float*)d_in[12];
  const float* fc_w      = (const float*)d_in[13];
  const float* fc_b      = (const float*)d_in[14];
  float* out = (float*)d_out;

  const int B    = in_sizes[0];
  const int E    = in_sizes[2] / 2;
  const int N    = in_sizes[4] / 64;
  const int NSRV = in_sizes[14];
  const int Etot = E + N;
  const int NCTX = in_sizes[1];  // B*CTX
  (void)B;

  const int* edge_src = edge_index;
  const int* edge_dst = edge_index + E;

  // ---- workspace layout ----
  char* ws = (char*)d_ws;
  size_t off = 0;
  auto alloc = [&](size_t bytes) {
    void* p = ws + off;
    off = (off + bytes + 255) & ~(size_t)255;
    return p;
  };
  const int NB = (N + NPB - 1) >> NPB_SH;   // 196 for N=100000 (requires <=256)
  unsigned short* h1 = (unsigned short*)alloc((size_t)N * 128 * 2);  // reused as h2
  float* g      = (float*)alloc((size_t)N * 128 * 4);                // reused as g2
  float* as1    = (float*)alloc((size_t)N * 2 * 4);
  float* ad1    = (float*)alloc((size_t)N * 2 * 4);
  float* as2    = (float*)alloc((size_t)N * 4);
  float* ad2    = (float*)alloc((size_t)N * 4);
  int*   rowptr = (int*)alloc((size_t)(N + 1) * 4);
  int*   adj    = (int*)alloc((size_t)Etot * 4);
  unsigned* rec = (unsigned*)alloc((size_t)NB * BCAP * 4);
  int* bucketBase   = (int*)alloc(257 * 4);
  int* bucketCursor = (int*)alloc(256 * 4);
  int* flagC  = (int*)alloc((size_t)N * 4);
  int* flag1  = (int*)alloc((size_t)N * 4);
  int* listC  = (int*)alloc((size_t)NCTX * 4);
  int* list1  = (int*)alloc((size_t)N * 4);
  int* cnt    = (int*)alloc(2 * 4);
  unsigned short* xb = (unsigned short*)alloc((size_t)512 * 256 * 2);
  unsigned short* h2 = h1;
  float* g2 = g;
  (void)ws_size;

  const int NBLK2 = 256;
  const int epb = (Etot + NBLK2 - 1) / NBLK2;
  const int nblk_N = (N + 255) / 256;
  const int nblk_E = (Etot + 255) / 256;

  // combined init (bucket cursors + frontier flags)
  k_init<<<nblk_N, 256, 0, stream>>>(bucketCursor, NB, flagC, flag1, cnt, N);

  // GAT layer 1 linear (full N — sources cover ~99% of nodes)
  k_h1<<<(N + 31) / 32, 256, 0, stream>>>(service_emb, W1, att_src1, att_dst1, h1, as1, ad1, N);

  // frontier: plain-store marking, then block-compaction (no hot atomics)
  k_markC<<<(NCTX + 255) / 256, 256, 0, stream>>>(context_idx, NCTX, flagC, flag1);
  k_markS1e<<<nblk_E, 256, 0, stream>>>(edge_src, edge_dst, E, Etot, flagC, flag1);
  k_compact<<<nblk_N, 256, 0, stream>>>(flagC, flag1, listC, list1, cnt, N);

  // CSR build, FILTERED to edges with dst in S1 (~27% of edges)
  k_bscatter<<<NBLK2, 1024, 0, stream>>>(edge_src, edge_dst, E, Etot, epb, flag1, bucketCursor, rec, NB);
  k_bscan2<<<1, 256, 0, stream>>>(bucketCursor, bucketBase, NB, rowptr, N);
  k_bcsr<<<NB, 1024, 0, stream>>>(rec, bucketBase, rowptr, adj, N, NB);

  // layer 1 aggregate -> g (elu'd), only for list1 nodes
  k_gat1<<<(N + 3) / 4, 256, 0, stream>>>(h1, as1, ad1, rowptr, adj, b1, g, list1, cnt);

  // layer 2 linear (h2 overlays h1), only for list1 nodes
  k_h2<<<(N + 31) / 32, 256, 0, stream>>>(g, W2, att_src2, att_dst2, h2, as2, ad2, list1, cnt);

  // layer 2 aggregate -> g2 (overlays g), only for C nodes
  k_gat2<<<(NCTX + 3) / 4, 256, 0, stream>>>(h2, as2, ad2, rowptr, adj, b2, g2, listC, cnt);

  // gather features -> bf16 K-blocked
  k_xmat<<<512, 256, 0, stream>>>(user_idx, context_idx, user_emb, g2, xb);

  // final FC (MFMA, A-persistent, double-buffered 32-col grid-strided tiles)
  const int nfct = (NSRV + 31) / 32;
  const int grid = 512;
  k_fc<<<grid, 512, 0, stream>>>(xb, fc_w, fc_b, out, NSRV, nfct, grid);
}

// Round 16
// 278.867 us; speedup vs baseline: 1.0044x; 1.0044x over previous
//
#include <hip/hip_runtime.h>
#include <hip/hip_bf16.h>
#include <math.h>

#define NEG_SLOPE 0.2f

// CSR binning parameters (N=100000, E+N~1.7M; requires N < 2^18 and NB <= 256)
#define NPB 512       // nodes per bucket
#define NPB_SH 9
#define SRC_BITS 18
#define LCAP 16384    // LDS adj staging capacity (edges) per bucket
#define BCAP 16384    // fixed per-bucket record capacity (filtered mean ~2.4K)

typedef __attribute__((ext_vector_type(8))) short short8;
typedef __attribute__((ext_vector_type(4))) float f32x4;

__device__ __forceinline__ float leaky(float x) { return x > 0.f ? x : NEG_SLOPE * x; }

__device__ __forceinline__ unsigned short f2bf(float f) {
  unsigned u = __float_as_uint(f);
  unsigned r = (u + 0x7FFFu + ((u >> 16) & 1u)) >> 16;  // RNE
  return (unsigned short)r;
}

// LDS-only barrier: orders ds ops across waves without draining global loads/stores.
#define LGKM_BARRIER()                                   \
  do {                                                   \
    asm volatile("s_waitcnt lgkmcnt(0)" ::: "memory");   \
    __builtin_amdgcn_s_barrier();                        \
  } while (0)

// ---------------- GAT layer 1 linear: h1[N,128] = x[N,64] @ W1[64,128] (bf16 out)
__global__ void k_h1(const float* __restrict__ x, const float* __restrict__ W1,
                     const float* __restrict__ att_src, const float* __restrict__ att_dst,
                     unsigned short* __restrict__ h1, float* __restrict__ a_s,
                     float* __restrict__ a_d, int N) {
  __shared__ __align__(16) float W1s[64 * 128];   // 32 KB
  __shared__ __align__(16) float xs[32][64];      // 8 KB
  const int tid = threadIdx.x;
  for (int i = tid; i < 64 * 128; i += 256) W1s[i] = W1[i];
  const int node0 = blockIdx.x * 32;
  for (int i = tid; i < 512; i += 256) {
    const int nn = node0 + (i >> 4);
    if (nn < N) ((float4*)xs)[i] = *(const float4*)(x + (size_t)nn * 64 + (i & 15) * 4);
  }
  const int ln  = tid >> 7;   // node slot 0/1
  const int col = tid & 127;  // output channel
  const int head = col >> 6;
  const int c = col & 63;
  const float as_w = att_src[head * 64 + c];
  const float ad_w = att_dst[head * 64 + c];
  __syncthreads();  // W1s + xs ready
  float wreg[64];
#pragma unroll
  for (int cc = 0; cc < 64; ++cc) wreg[cc] = W1s[cc * 128 + col];

  for (int it = 0; it < 16; ++it) {
    const int slot = it * 2 + ln;
    const int n = node0 + slot;
    if (n >= N) continue;
    float acc = 0.f;
#pragma unroll
    for (int q = 0; q < 16; ++q) {
      const float4 xv = *(const float4*)&xs[slot][q * 4];
      acc = fmaf(xv.x, wreg[q * 4 + 0], acc);
      acc = fmaf(xv.y, wreg[q * 4 + 1], acc);
      acc = fmaf(xv.z, wreg[q * 4 + 2], acc);
      acc = fmaf(xv.w, wreg[q * 4 + 3], acc);
    }
    h1[(size_t)n * 128 + col] = f2bf(acc);
    float vs = acc * as_w;
    float vd = acc * ad_w;
#pragma unroll
    for (int off = 32; off > 0; off >>= 1) {
      vs += __shfl_down(vs, off, 64);
      vd += __shfl_down(vd, off, 64);
    }
    if (c == 0) { a_s[n * 2 + head] = vs; a_d[n * 2 + head] = vd; }
  }
}

// ---------------- combined init: bucket cursors + frontier flags + counters ----------
__global__ void k_init(int* __restrict__ cursor, int NB, int* __restrict__ flagC,
                       int* __restrict__ flag1, int* __restrict__ cnt, int N) {
  const int i = blockIdx.x * 256 + threadIdx.x;
  if (i < NB) cursor[i] = i * BCAP;
  if (i < N) { flagC[i] = 0; flag1[i] = 0; }
  if (i < 2) cnt[i] = 0;
}

// ---------------- demand-driven frontier: plain-store marking (no atomics) ----------
__global__ void k_markC(const int* __restrict__ ctx, int nctx, int* __restrict__ flagC,
                        int* __restrict__ flag1) {
  const int i = blockIdx.x * 256 + threadIdx.x;
  if (i >= nctx) return;
  const int n = ctx[i];
  flagC[n] = 1;   // idempotent
  flag1[n] = 1;
}

// edge-scan: flag1 |= {src[e] : dst[e] ∈ C}. Plain stores, fire-and-forget.
__global__ void k_markS1e(const int* __restrict__ src, const int* __restrict__ dst,
                          int E, int Etot, const int* __restrict__ flagC,
                          int* __restrict__ flag1) {
  const int e = blockIdx.x * 256 + threadIdx.x;
  if (e >= Etot) return;
  int s, d;
  if (e < E) { s = src[e]; d = dst[e]; } else { s = d = e - E; }
  if (flagC[d]) flag1[s] = 1;
}

// compaction: flags -> lists. One global atomicAdd per block per list.
__global__ void k_compact(const int* __restrict__ flagC, const int* __restrict__ flag1,
                          int* __restrict__ listC, int* __restrict__ list1,
                          int* __restrict__ cnt, int N) {
  __shared__ int lc, l1, bc, b1;
  const int i = blockIdx.x * 256 + threadIdx.x;
  if (threadIdx.x == 0) { lc = 0; l1 = 0; }
  __syncthreads();
  int pc = -1, p1 = -1;
  if (i < N) {
    if (flagC[i]) pc = atomicAdd(&lc, 1);
    if (flag1[i]) p1 = atomicAdd(&l1, 1);
  }
  __syncthreads();
  if (threadIdx.x == 0) {
    bc = lc ? atomicAdd(&cnt[0], lc) : 0;
    b1 = l1 ? atomicAdd(&cnt[1], l1) : 0;
  }
  __syncthreads();
  if (pc >= 0) listC[bc + pc] = i;
  if (p1 >= 0) list1[b1 + p1] = i;
}

// ---------------- CSR build, FILTERED to rows in S1 (flag1[dst]) ----------------
__global__ __launch_bounds__(1024) void k_bscatter(const int* __restrict__ src,
                                                   const int* __restrict__ dst, int E, int Etot,
                                                   int epb, const int* __restrict__ flag1,
                                                   int* __restrict__ cursor,
                                                   unsigned* __restrict__ rec, int NB) {
  __shared__ int hist[256];
  __shared__ int cur[256];
  const int tid = threadIdx.x;
  if (tid < 256) hist[tid] = 0;
  __syncthreads();
  const int e0 = blockIdx.x * epb;
  const int e1 = min(e0 + epb, Etot);
  for (int e = e0 + tid; e < e1; e += 1024) {
    const int d = (e < E) ? dst[e] : (e - E);
    if (flag1[d]) atomicAdd(&hist[d >> NPB_SH], 1);
  }
  __syncthreads();
  if (tid < NB) {
    const int c = hist[tid];
    cur[tid] = c ? atomicAdd(&cursor[tid], c) : 0;
  }
  __syncthreads();
  for (int e = e0 + tid; e < e1; e += 1024) {
    int sv, d;
    if (e < E) { sv = src[e]; d = dst[e]; } else { sv = d = e - E; }
    if (!flag1[d]) continue;
    const int b = d >> NPB_SH;
    const int p = atomicAdd(&cur[b], 1);
    rec[p] = (unsigned)sv | ((unsigned)(d & (NPB - 1)) << SRC_BITS);
  }
}

// one block per bucket: recompute bucket prefix from cursor deltas (folds old
// k_bscan2), then local degree count, scan, LDS scatter, coalesced copy out.
__global__ __launch_bounds__(1024) void k_bcsr(const unsigned* __restrict__ rec,
                                               const int* __restrict__ cursor,
                                               int* __restrict__ rowptr, int* __restrict__ adj,
                                               int N, int NB) {
  __shared__ int ldeg[NPB];
  __shared__ int s[NPB];
  __shared__ int ladj[LCAP];
  __shared__ int o0s, cnts;
  const int b = blockIdx.x;
  const int tid = threadIdx.x;

  // bucket-count inclusive scan over NB (<=256) entries, reusing s[0..255]
  if (tid < 256) s[tid] = (tid < NB) ? (cursor[tid] - tid * BCAP) : 0;
  __syncthreads();
  for (int off = 1; off < 256; off <<= 1) {
    int t = 0;
    if (tid < 256 && tid >= off) t = s[tid - off];
    __syncthreads();
    if (tid < 256) s[tid] += t;
    __syncthreads();
  }
  if (tid == 0) {
    const int cb = cursor[b] - b * BCAP;
    o0s = s[b] - cb;
    cnts = cb;
    if (b == 0) rowptr[N] = s[NB - 1];
  }
  __syncthreads();
  const int o0 = o0s;
  const int cnt = cnts;
  const int r0 = b * BCAP;

  if (tid < NPB) ldeg[tid] = 0;
  __syncthreads();
  for (int i = tid; i < cnt; i += 1024)
    atomicAdd(&ldeg[rec[r0 + i] >> SRC_BITS], 1);
  __syncthreads();
  int v = 0;
  if (tid < NPB) { v = ldeg[tid]; s[tid] = v; }
  __syncthreads();
  for (int off = 1; off < NPB; off <<= 1) {
    int t = 0;
    if (tid < NPB && tid >= off) t = s[tid - off];
    __syncthreads();
    if (tid < NPB) s[tid] += t;
    __syncthreads();
  }
  if (tid < NPB) {
    const int excl = s[tid] - v;
    const int node = b * NPB + tid;
    if (node < N) rowptr[node] = o0 + excl;
    ldeg[tid] = excl;  // reuse as scatter cursor
  }
  __syncthreads();
  if (cnt <= LCAP) {
    for (int i = tid; i < cnt; i += 1024) {
      const unsigned r = rec[r0 + i];
      const int p = atomicAdd(&ldeg[r >> SRC_BITS], 1);
      ladj[p] = (int)(r & ((1u << SRC_BITS) - 1));
    }
    __syncthreads();
    for (int i = tid; i < cnt; i += 1024) adj[o0 + i] = ladj[i];
  } else {  // safety fallback (never expected)
    for (int i = tid; i < cnt; i += 1024) {
      const unsigned r = rec[r0 + i];
      const int p = atomicAdd(&ldeg[r >> SRC_BITS], 1);
      adj[o0 + p] = (int)(r & ((1u << SRC_BITS) - 1));
    }
  }
}

// ---------------- GAT layer 1 aggregate over list1 (x4 unroll) -------
__global__ void k_gat1(const unsigned short* __restrict__ h1, const float* __restrict__ as1,
                       const float* __restrict__ ad1, const int* __restrict__ rowptr,
                       const int* __restrict__ adj, const float* __restrict__ b1,
                       float* __restrict__ g, const int* __restrict__ list1,
                       const int* __restrict__ cnt) {
  const int w = threadIdx.x >> 6;
  const int l = threadIdx.x & 63;
  const int idx = blockIdx.x * 4 + w;
  if (idx >= cnt[1]) return;
  const int n = list1[idx];
  const int half = l >> 5;
  const int q = l & 31;       // channels 4q..4q+3
  const int head = q >> 4;
  const float adh = ad1[n * 2 + head];
  float a0 = 0.f, a1 = 0.f, a2 = 0.f, a3 = 0.f, dsum = 0.f;
  const int kb = rowptr[n], ke = rowptr[n + 1];
  const int kend = ke - 1;
  for (int k = kb + half; k < ke; k += 8) {
    const int e1 = k + 2, e2 = k + 4, e3 = k + 6;
    const int s0 = adj[k];
    const int s1 = adj[min(e1, kend)];
    const int s2 = adj[min(e2, kend)];
    const int s3 = adj[min(e3, kend)];
    const float x0 = as1[s0 * 2 + head] + adh;
    const float x1 = as1[s1 * 2 + head] + adh;
    const float x2 = as1[s2 * 2 + head] + adh;
    const float x3 = as1[s3 * 2 + head] + adh;
    const uint2 u0 = *(const uint2*)(h1 + (size_t)s0 * 128 + 4 * q);
    const uint2 u1 = *(const uint2*)(h1 + (size_t)s1 * 128 + 4 * q);
    const uint2 u2 = *(const uint2*)(h1 + (size_t)s2 * 128 + 4 * q);
    const uint2 u3 = *(const uint2*)(h1 + (size_t)s3 * 128 + 4 * q);
    const float w0 = __expf(leaky(x0));
    const float w1 = (e1 < ke) ? __expf(leaky(x1)) : 0.f;
    const float w2 = (e2 < ke) ? __expf(leaky(x2)) : 0.f;
    const float w3 = (e3 < ke) ? __expf(leaky(x3)) : 0.f;
    dsum += (w0 + w1) + (w2 + w3);
    a0 = fmaf(w0, __uint_as_float(u0.x << 16), a0);
    a1 = fmaf(w0, __uint_as_float(u0.x & 0xFFFF0000u), a1);
    a2 = fmaf(w0, __uint_as_float(u0.y << 16), a2);
    a3 = fmaf(w0, __uint_as_float(u0.y & 0xFFFF0000u), a3);
    a0 = fmaf(w1, __uint_as_float(u1.x << 16), a0);
    a1 = fmaf(w1, __uint_as_float(u1.x & 0xFFFF0000u), a1);
    a2 = fmaf(w1, __uint_as_float(u1.y << 16), a2);
    a3 = fmaf(w1, __uint_as_float(u1.y & 0xFFFF0000u), a3);
    a0 = fmaf(w2, __uint_as_float(u2.x << 16), a0);
    a1 = fmaf(w2, __uint_as_float(u2.x & 0xFFFF0000u), a1);
    a2 = fmaf(w2, __uint_as_float(u2.y << 16), a2);
    a3 = fmaf(w2, __uint_as_float(u2.y & 0xFFFF0000u), a3);
    a0 = fmaf(w3, __uint_as_float(u3.x << 16), a0);
    a1 = fmaf(w3, __uint_as_float(u3.x & 0xFFFF0000u), a1);
    a2 = fmaf(w3, __uint_as_float(u3.y << 16), a2);
    a3 = fmaf(w3, __uint_as_float(u3.y & 0xFFFF0000u), a3);
  }
  a0 += __shfl_xor(a0, 32, 64);
  a1 += __shfl_xor(a1, 32, 64);
  a2 += __shfl_xor(a2, 32, 64);
  a3 += __shfl_xor(a3, 32, 64);
  dsum += __shfl_xor(dsum, 32, 64);
  if (half == 0) {
    const float inv = 1.f / (dsum + 1e-16f);
    const float4 bv = *(const float4*)(b1 + 4 * q);
    float g0 = fmaf(a0, inv, bv.x);
    float g1 = fmaf(a1, inv, bv.y);
    float g2v = fmaf(a2, inv, bv.z);
    float g3 = fmaf(a3, inv, bv.w);
    g0 = g0 > 0.f ? g0 : expm1f(g0);
    g1 = g1 > 0.f ? g1 : expm1f(g1);
    g2v = g2v > 0.f ? g2v : expm1f(g2v);
    g3 = g3 > 0.f ? g3 : expm1f(g3);
    *(float4*)(g + (size_t)n * 128 + 4 * q) = make_float4(g0, g1, g2v, g3);
  }
}

// ---------------- GAT layer 2 linear over list1: h2 = g @ W2 (bf16 out)
__global__ void k_h2(const float* __restrict__ g, const float* __restrict__ W2,
                     const float* __restrict__ att_s, const float* __restrict__ att_d,
                     unsigned short* __restrict__ h2, float* __restrict__ a_s,
                     float* __restrict__ a_d, const int* __restrict__ list1,
                     const int* __restrict__ cnt) {
  const int cnt1 = cnt[1];
  const int base0 = blockIdx.x * 32;
  if (base0 >= cnt1) return;
  __shared__ __align__(16) float W2s[128 * 64];
  __shared__ __align__(16) float gs[2][128];
  __shared__ float part[2][64];
  for (int i = threadIdx.x; i < 128 * 64; i += 256) W2s[i] = W2[i];
  const int col = threadIdx.x & 63;
  const int kh  = (threadIdx.x >> 6) & 1;
  const int ln  = threadIdx.x >> 7;
  const float as_w = att_s[col], ad_w = att_d[col];
  __syncthreads();
  float wreg[64];
#pragma unroll
  for (int cc = 0; cc < 64; ++cc) wreg[cc] = W2s[(kh * 64 + cc) * 64 + col];

  for (int it = 0; it < 16; ++it) {
    const int sbase = base0 + it * 2;
    __syncthreads();
    {
      const int slot = sbase + (threadIdx.x >> 7);
      if (slot < cnt1) {
        const int nn = list1[slot];
        gs[threadIdx.x >> 7][threadIdx.x & 127] = g[(size_t)nn * 128 + (threadIdx.x & 127)];
      }
    }
    __syncthreads();
    const int slot = sbase + ln;
    const int n = (slot < cnt1) ? list1[slot] : -1;
    float acc = 0.f;
    if (n >= 0) {
#pragma unroll
      for (int q = 0; q < 16; ++q) {
        const float4 gv = *(const float4*)&gs[ln][kh * 64 + q * 4];
        acc = fmaf(gv.x, wreg[q * 4 + 0], acc);
        acc = fmaf(gv.y, wreg[q * 4 + 1], acc);
        acc = fmaf(gv.z, wreg[q * 4 + 2], acc);
        acc = fmaf(gv.w, wreg[q * 4 + 3], acc);
      }
    }
    if (kh == 1) part[ln][col] = acc;
    __syncthreads();
    if (kh == 0 && n >= 0) {
      acc += part[ln][col];
      h2[(size_t)n * 64 + col] = f2bf(acc);
      float vs = acc * as_w, vd = acc * ad_w;
#pragma unroll
      for (int off = 32; off > 0; off >>= 1) {
        vs += __shfl_down(vs, off, 64);
        vd += __shfl_down(vd, off, 64);
      }
      if (col == 0) { a_s[n] = vs; a_d[n] = vd; }
    }
  }
}

// ---------------- GAT layer 2 aggregate over listC (x4 unroll) ----------------
__global__ void k_gat2(const unsigned short* __restrict__ h2, const float* __restrict__ as2,
                       const float* __restrict__ ad2, const int* __restrict__ rowptr,
                       const int* __restrict__ adj, const float* __restrict__ b2,
                       float* __restrict__ g2, const int* __restrict__ listC,
                       const int* __restrict__ cnt) {
  const int w = threadIdx.x >> 6;
  const int l = threadIdx.x & 63;
  const int idx = blockIdx.x * 4 + w;
  if (idx >= cnt[0]) return;
  const int n = listC[idx];
  const int half = l >> 5;
  const int q = l & 31;       // channels 2q, 2q+1
  const float adh = ad2[n];
  float a0 = 0.f, a1 = 0.f, dsum = 0.f;
  const int kb = rowptr[n], ke = rowptr[n + 1];
  const int kend = ke - 1;
  for (int k = kb + half; k < ke; k += 8) {
    const int e1 = k + 2, e2 = k + 4, e3 = k + 6;
    const int s0 = adj[k];
    const int s1 = adj[min(e1, kend)];
    const int s2 = adj[min(e2, kend)];
    const int s3 = adj[min(e3, kend)];
    const float x0 = as2[s0] + adh;
    const float x1 = as2[s1] + adh;
    const float x2 = as2[s2] + adh;
    const float x3 = as2[s3] + adh;
    const unsigned u0 = *(const unsigned*)(h2 + (size_t)s0 * 64 + 2 * q);
    const unsigned u1 = *(const unsigned*)(h2 + (size_t)s1 * 64 + 2 * q);
    const unsigned u2 = *(const unsigned*)(h2 + (size_t)s2 * 64 + 2 * q);
    const unsigned u3 = *(const unsigned*)(h2 + (size_t)s3 * 64 + 2 * q);
    const float w0 = __expf(leaky(x0));
    const float w1 = (e1 < ke) ? __expf(leaky(x1)) : 0.f;
    const float w2 = (e2 < ke) ? __expf(leaky(x2)) : 0.f;
    const float w3 = (e3 < ke) ? __expf(leaky(x3)) : 0.f;
    dsum += (w0 + w1) + (w2 + w3);
    a0 = fmaf(w0, __uint_as_float(u0 << 16), a0);
    a1 = fmaf(w0, __uint_as_float(u0 & 0xFFFF0000u), a1);
    a0 = fmaf(w1, __uint_as_float(u1 << 16), a0);
    a1 = fmaf(w1, __uint_as_float(u1 & 0xFFFF0000u), a1);
    a0 = fmaf(w2, __uint_as_float(u2 << 16), a0);
    a1 = fmaf(w2, __uint_as_float(u2 & 0xFFFF0000u), a1);
    a0 = fmaf(w3, __uint_as_float(u3 << 16), a0);
    a1 = fmaf(w3, __uint_as_float(u3 & 0xFFFF0000u), a1);
  }
  a0 += __shfl_xor(a0, 32, 64);
  a1 += __shfl_xor(a1, 32, 64);
  dsum += __shfl_xor(dsum, 32, 64);
  if (half == 0) {
    const float inv = 1.f / (dsum + 1e-16f);
    const float2 bv = *(const float2*)(b2 + 2 * q);
    ((float2*)g2)[(size_t)n * 32 + q] =
        make_float2(fmaf(a0, inv, bv.x), fmaf(a1, inv, bv.y));
  }
}

// ---------------- build x matrix, bf16, K-blocked: xb[k/32][512][32] ----------------
__global__ void k_xmat(const int* __restrict__ user_idx, const int* __restrict__ ctx_idx,
                       const float* __restrict__ user_emb, const float* __restrict__ g2,
                       unsigned short* __restrict__ xb) {
  const int b = blockIdx.x;
  const int k = threadIdx.x;  // 0..255
  float v;
  if (k < 64) {
    v = user_emb[(size_t)user_idx[b] * 64 + k];
  } else {
    const int c = (k - 64) >> 6;
    v = g2[(size_t)ctx_idx[b * 3 + c] * 64 + (k & 63)];
  }
  xb[(size_t)(k >> 5) * (512 * 32) + b * 32 + (k & 31)] = f2bf(v);
}

// ---------------- final FC via MFMA, A-persistent, dbuf LDS ------------------------
// Staging re-indexed: thread owns (col sc, contiguous k-chunk) -> writev is
// 2x ds_write_b128 per thread per tile (was 16 scalar ds_write_b16).
__global__ __launch_bounds__(512) void k_fc(const unsigned short* __restrict__ xb,
                                            const float* __restrict__ fc_w,
                                            const float* __restrict__ fc_b,
                                            float* __restrict__ out, int NSRV,
                                            int ntiles, int gstride) {
  __shared__ __align__(16) unsigned short Blds[2][32 * 264];  // 33 KB

  const int tid = threadIdx.x;
  const int w = tid >> 6;
  const int lane = tid & 63;
  const int l15 = lane & 15;
  const int kg = lane >> 4;

  if (blockIdx.x >= (unsigned)ntiles) return;

  // persistent A fragments (serve as the MFMA *B* operand after the swap)
  short8 afr[4][8];
#pragma unroll
  for (int mf = 0; mf < 4; ++mf) {
    const int row = w * 64 + mf * 16 + l15;
#pragma unroll
    for (int ks = 0; ks < 8; ++ks) {
      afr[mf][ks] = *(const short8*)(xb + (size_t)ks * 16384 + row * 32 + kg * 8);
    }
  }

  const int sc  = tid & 31;          // stage: col in tile
  const int sk0 = (tid >> 5) * 16;   // stage: contiguous k-chunk base (0,16,..,240)

  float v[16];
  auto loadv = [&](int t) {
    const int cg = t * 32 + sc;
    const bool okc = cg < NSRV;
#pragma unroll
    for (int i = 0; i < 16; ++i)
      v[i] = okc ? __builtin_nontemporal_load(fc_w + (size_t)(sk0 + i) * NSRV + cg) : 0.f;
  };
  auto writev = [&](int buf) {
    short8 lo, hi;
#pragma unroll
    for (int i = 0; i < 8; ++i) { lo[i] = (short)f2bf(v[i]); hi[i] = (short)f2bf(v[8 + i]); }
    *(short8*)&Blds[buf][sc * 264 + sk0]     = lo;
    *(short8*)&Blds[buf][sc * 264 + sk0 + 8] = hi;
  };

  // prologue: tile t0 staged, loads for t0+gs in flight
  loadv(blockIdx.x);
  writev(0);
  if (blockIdx.x + gstride < ntiles) loadv(blockIdx.x + gstride);
  LGKM_BARRIER();

  int cur = 0;
  for (int t = blockIdx.x; t < ntiles; t += gstride) {
    if (t + gstride < ntiles) writev(cur ^ 1);   // consumes loads issued a tile ago
    if (t + 2 * gstride < ntiles) loadv(t + 2 * gstride);
    const int j0 = t * 32;
#pragma unroll
    for (int nf = 0; nf < 2; ++nf) {
      short8 bfr[8];
#pragma unroll
      for (int ks = 0; ks < 8; ++ks)
        bfr[ks] = *(const short8*)&Blds[cur][(nf * 16 + l15) * 264 + ks * 32 + kg * 8];
      f32x4 acc[4];
#pragma unroll
      for (int mf = 0; mf < 4; ++mf) acc[mf] = (f32x4){0.f, 0.f, 0.f, 0.f};
#pragma unroll
      for (int ks = 0; ks < 8; ++ks)
#pragma unroll
        for (int mf = 0; mf < 4; ++mf)
          acc[mf] = __builtin_amdgcn_mfma_f32_16x16x32_bf16(bfr[ks], afr[mf][ks], acc[mf], 0, 0, 0);
      const int jc = j0 + nf * 16 + kg * 4;
      if (j0 + 32 <= NSRV) {
        const float4 bias = *(const float4*)(fc_b + jc);
#pragma unroll
        for (int mf = 0; mf < 4; ++mf) {
          const int row = w * 64 + mf * 16 + l15;
          f32x4 o;
          o[0] = acc[mf][0] + bias.x;
          o[1] = acc[mf][1] + bias.y;
          o[2] = acc[mf][2] + bias.z;
          o[3] = acc[mf][3] + bias.w;
          __builtin_nontemporal_store(o, (f32x4*)(out + (size_t)row * NSRV + jc));
        }
      } else {
#pragma unroll
        for (int mf = 0; mf < 4; ++mf) {
          const int row = w * 64 + mf * 16 + l15;
#pragma unroll
          for (int r = 0; r < 4; ++r) {
            const int j = jc + r;
            if (j < NSRV) out[(size_t)row * NSRV + j] = acc[mf][r] + fc_b[j];
          }
        }
      }
    }
    LGKM_BARRIER();
    cur ^= 1;
  }
}

// =====================================================================
extern "C" void kernel_launch(void* const* d_in, const int* in_sizes, int n_in,
                              void* d_out, int out_size, void* d_ws, size_t ws_size,
                              hipStream_t stream) {
  const int* user_idx    = (const int*)d_in[0];
  const int* context_idx = (const int*)d_in[1];
  const int* edge_index  = (const int*)d_in[2];
  const float* user_emb  = (const float*)d_in[3];
  const float* service_emb = (const float*)d_in[4];
  const float* W1        = (const float*)d_in[5];
  const float* att_src1  = (const float*)d_in[6];
  const float* att_dst1  = (const float*)d_in[7];
  const float* b1        = (const float*)d_in[8];
  const float* W2        = (const float*)d_in[9];
  const float* att_src2  = (const float*)d_in[10];
  const float* att_dst2  = (const float*)d_in[11];
  const float* b2        = (const float*)d_in[12];
  const float* fc_w      = (const float*)d_in[13];
  const float* fc_b      = (const float*)d_in[14];
  float* out = (float*)d_out;

  const int B    = in_sizes[0];
  const int E    = in_sizes[2] / 2;
  const int N    = in_sizes[4] / 64;
  const int NSRV = in_sizes[14];
  const int Etot = E + N;
  const int NCTX = in_sizes[1];  // B*CTX
  (void)B;

  const int* edge_src = edge_index;
  const int* edge_dst = edge_index + E;

  // ---- workspace layout ----
  char* ws = (char*)d_ws;
  size_t off = 0;
  auto alloc = [&](size_t bytes) {
    void* p = ws + off;
    off = (off + bytes + 255) & ~(size_t)255;
    return p;
  };
  const int NB = (N + NPB - 1) >> NPB_SH;   // 196 for N=100000 (requires <=256)
  unsigned short* h1 = (unsigned short*)alloc((size_t)N * 128 * 2);  // reused as h2
  float* g      = (float*)alloc((size_t)N * 128 * 4);                // reused as g2
  float* as1    = (float*)alloc((size_t)N * 2 * 4);
  float* ad1    = (float*)alloc((size_t)N * 2 * 4);
  float* as2    = (float*)alloc((size_t)N * 4);
  float* ad2    = (float*)alloc((size_t)N * 4);
  int*   rowptr = (int*)alloc((size_t)(N + 1) * 4);
  int*   adj    = (int*)alloc((size_t)Etot * 4);
  unsigned* rec = (unsigned*)alloc((size_t)NB * BCAP * 4);
  int* bucketCursor = (int*)alloc(256 * 4);
  int* flagC  = (int*)alloc((size_t)N * 4);
  int* flag1  = (int*)alloc((size_t)N * 4);
  int* listC  = (int*)alloc((size_t)NCTX * 4);
  int* list1  = (int*)alloc((size_t)N * 4);
  int* cnt    = (int*)alloc(2 * 4);
  unsigned short* xb = (unsigned short*)alloc((size_t)512 * 256 * 2);
  unsigned short* h2 = h1;
  float* g2 = g;
  (void)ws_size;

  const int NBLK2 = 256;
  const int epb = (Etot + NBLK2 - 1) / NBLK2;
  const int nblk_N = (N + 255) / 256;
  const int nblk_E = (Etot + 255) / 256;

  // combined init (bucket cursors + frontier flags)
  k_init<<<nblk_N, 256, 0, stream>>>(bucketCursor, NB, flagC, flag1, cnt, N);

  // GAT layer 1 linear (full N — sources cover ~99% of nodes)
  k_h1<<<(N + 31) / 32, 256, 0, stream>>>(service_emb, W1, att_src1, att_dst1, h1, as1, ad1, N);

  // frontier: plain-store marking, then block-compaction (no hot atomics)
  k_markC<<<(NCTX + 255) / 256, 256, 0, stream>>>(context_idx, NCTX, flagC, flag1);
  k_markS1e<<<nblk_E, 256, 0, stream>>>(edge_src, edge_dst, E, Etot, flagC, flag1);
  k_compact<<<nblk_N, 256, 0, stream>>>(flagC, flag1, listC, list1, cnt, N);

  // CSR build, FILTERED to edges with dst in S1 (~27% of edges)
  k_bscatter<<<NBLK2, 1024, 0, stream>>>(edge_src, edge_dst, E, Etot, epb, flag1, bucketCursor, rec, NB);
  k_bcsr<<<NB, 1024, 0, stream>>>(rec, bucketCursor, rowptr, adj, N, NB);

  // layer 1 aggregate -> g (elu'd), only for list1 nodes
  k_gat1<<<(N + 3) / 4, 256, 0, stream>>>(h1, as1, ad1, rowptr, adj, b1, g, list1, cnt);

  // layer 2 linear (h2 overlays h1), only for list1 nodes
  k_h2<<<(N + 31) / 32, 256, 0, stream>>>(g, W2, att_src2, att_dst2, h2, as2, ad2, list1, cnt);

  // layer 2 aggregate -> g2 (overlays g), only for C nodes
  k_gat2<<<(NCTX + 3) / 4, 256, 0, stream>>>(h2, as2, ad2, rowptr, adj, b2, g2, listC, cnt);

  // gather features -> bf16 K-blocked
  k_xmat<<<512, 256, 0, stream>>>(user_idx, context_idx, user_emb, g2, xb);

  // final FC (MFMA, A-persistent, double-buffered 32-col grid-strided tiles)
  const int nfct = (NSRV + 31) / 32;
  const int grid = 512;
  k_fc<<<grid, 512, 0, stream>>>(xb, fc_w, fc_b, out, NSRV, nfct, grid);
}

// Round 17
// 277.999 us; speedup vs baseline: 1.0075x; 1.0031x over previous
//
#include <hip/hip_runtime.h>
#include <hip/hip_bf16.h>
#include <math.h>

#define NEG_SLOPE 0.2f

// CSR binning parameters (N=100000, E+N~1.7M; requires N < 2^18 and NB <= 256)
#define NPB 512       // nodes per bucket
#define NPB_SH 9
#define SRC_BITS 18
#define LCAP 16384    // LDS adj staging capacity (edges) per bucket
#define BCAP 16384    // fixed per-bucket record capacity (filtered mean ~2.4K)

typedef __attribute__((ext_vector_type(8))) short short8;
typedef __attribute__((ext_vector_type(4))) float f32x4;

__device__ __forceinline__ float leaky(float x) { return x > 0.f ? x : NEG_SLOPE * x; }

__device__ __forceinline__ unsigned short f2bf(float f) {
  unsigned u = __float_as_uint(f);
  unsigned r = (u + 0x7FFFu + ((u >> 16) & 1u)) >> 16;  // RNE
  return (unsigned short)r;
}

// LDS-only barrier: orders ds ops across waves without draining global loads/stores.
#define LGKM_BARRIER()                                   \
  do {                                                   \
    asm volatile("s_waitcnt lgkmcnt(0)" ::: "memory");   \
    __builtin_amdgcn_s_barrier();                        \
  } while (0)

// ---------------- GAT layer 1 linear: h1[N,128] = x[N,64] @ W1[64,128] (bf16 out)
__global__ void k_h1(const float* __restrict__ x, const float* __restrict__ W1,
                     const float* __restrict__ att_src, const float* __restrict__ att_dst,
                     unsigned short* __restrict__ h1, float* __restrict__ a_s,
                     float* __restrict__ a_d, int N) {
  __shared__ __align__(16) float W1s[64 * 128];   // 32 KB
  __shared__ __align__(16) float xs[32][64];      // 8 KB
  const int tid = threadIdx.x;
  for (int i = tid; i < 64 * 128; i += 256) W1s[i] = W1[i];
  const int node0 = blockIdx.x * 32;
  for (int i = tid; i < 512; i += 256) {
    const int nn = node0 + (i >> 4);
    if (nn < N) ((float4*)xs)[i] = *(const float4*)(x + (size_t)nn * 64 + (i & 15) * 4);
  }
  const int ln  = tid >> 7;   // node slot 0/1
  const int col = tid & 127;  // output channel
  const int head = col >> 6;
  const int c = col & 63;
  const float as_w = att_src[head * 64 + c];
  const float ad_w = att_dst[head * 64 + c];
  __syncthreads();  // W1s + xs ready
  float wreg[64];
#pragma unroll
  for (int cc = 0; cc < 64; ++cc) wreg[cc] = W1s[cc * 128 + col];

  for (int it = 0; it < 16; ++it) {
    const int slot = it * 2 + ln;
    const int n = node0 + slot;
    if (n >= N) continue;
    float acc = 0.f;
#pragma unroll
    for (int q = 0; q < 16; ++q) {
      const float4 xv = *(const float4*)&xs[slot][q * 4];
      acc = fmaf(xv.x, wreg[q * 4 + 0], acc);
      acc = fmaf(xv.y, wreg[q * 4 + 1], acc);
      acc = fmaf(xv.z, wreg[q * 4 + 2], acc);
      acc = fmaf(xv.w, wreg[q * 4 + 3], acc);
    }
    h1[(size_t)n * 128 + col] = f2bf(acc);
    float vs = acc * as_w;
    float vd = acc * ad_w;
#pragma unroll
    for (int off = 32; off > 0; off >>= 1) {
      vs += __shfl_down(vs, off, 64);
      vd += __shfl_down(vd, off, 64);
    }
    if (c == 0) { a_s[n * 2 + head] = vs; a_d[n * 2 + head] = vd; }
  }
}

// ---------------- combined init: bucket cursors + frontier flags + counters ----------
__global__ void k_init(int* __restrict__ cursor, int NB, int* __restrict__ flagC,
                       int* __restrict__ flag1, int* __restrict__ cnt, int N) {
  const int i = blockIdx.x * 256 + threadIdx.x;
  if (i < NB) cursor[i] = i * BCAP;
  if (i < N) { flagC[i] = 0; flag1[i] = 0; }
  if (i < 2) cnt[i] = 0;
}

// ---------------- demand-driven frontier: plain-store marking (no atomics) ----------
__global__ void k_markC(const int* __restrict__ ctx, int nctx, int* __restrict__ flagC,
                        int* __restrict__ flag1) {
  const int i = blockIdx.x * 256 + threadIdx.x;
  if (i >= nctx) return;
  const int n = ctx[i];
  flagC[n] = 1;   // idempotent
  flag1[n] = 1;
}

// edge-scan: flag1 |= {src[e] : dst[e] ∈ C}. Plain stores, fire-and-forget.
__global__ void k_markS1e(const int* __restrict__ src, const int* __restrict__ dst,
                          int E, int Etot, const int* __restrict__ flagC,
                          int* __restrict__ flag1) {
  const int e = blockIdx.x * 256 + threadIdx.x;
  if (e >= Etot) return;
  int s, d;
  if (e < E) { s = src[e]; d = dst[e]; } else { s = d = e - E; }
  if (flagC[d]) flag1[s] = 1;
}

// compaction: flags -> lists. One global atomicAdd per block per list.
__global__ void k_compact(const int* __restrict__ flagC, const int* __restrict__ flag1,
                          int* __restrict__ listC, int* __restrict__ list1,
                          int* __restrict__ cnt, int N) {
  __shared__ int lc, l1, bc, b1;
  const int i = blockIdx.x * 256 + threadIdx.x;
  if (threadIdx.x == 0) { lc = 0; l1 = 0; }
  __syncthreads();
  int pc = -1, p1 = -1;
  if (i < N) {
    if (flagC[i]) pc = atomicAdd(&lc, 1);
    if (flag1[i]) p1 = atomicAdd(&l1, 1);
  }
  __syncthreads();
  if (threadIdx.x == 0) {
    bc = lc ? atomicAdd(&cnt[0], lc) : 0;
    b1 = l1 ? atomicAdd(&cnt[1], l1) : 0;
  }
  __syncthreads();
  if (pc >= 0) listC[bc + pc] = i;
  if (p1 >= 0) list1[b1 + p1] = i;
}

// ---------------- CSR build, FILTERED to rows in S1 (flag1[dst]) ----------------
__global__ __launch_bounds__(1024) void k_bscatter(const int* __restrict__ src,
                                                   const int* __restrict__ dst, int E, int Etot,
                                                   int epb, const int* __restrict__ flag1,
                                                   int* __restrict__ cursor,
                                                   unsigned* __restrict__ rec, int NB) {
  __shared__ int hist[256];
  __shared__ int cur[256];
  const int tid = threadIdx.x;
  if (tid < 256) hist[tid] = 0;
  __syncthreads();
  const int e0 = blockIdx.x * epb;
  const int e1 = min(e0 + epb, Etot);
  for (int e = e0 + tid; e < e1; e += 1024) {
    const int d = (e < E) ? dst[e] : (e - E);
    if (flag1[d]) atomicAdd(&hist[d >> NPB_SH], 1);
  }
  __syncthreads();
  if (tid < NB) {
    const int c = hist[tid];
    cur[tid] = c ? atomicAdd(&cursor[tid], c) : 0;
  }
  __syncthreads();
  for (int e = e0 + tid; e < e1; e += 1024) {
    int sv, d;
    if (e < E) { sv = src[e]; d = dst[e]; } else { sv = d = e - E; }
    if (!flag1[d]) continue;
    const int b = d >> NPB_SH;
    const int p = atomicAdd(&cur[b], 1);
    rec[p] = (unsigned)sv | ((unsigned)(d & (NPB - 1)) << SRC_BITS);
  }
}

// one block per bucket: recompute bucket prefix from cursor deltas, then local
// degree count, scan, LDS scatter, coalesced copy out.
__global__ __launch_bounds__(1024) void k_bcsr(const unsigned* __restrict__ rec,
                                               const int* __restrict__ cursor,
                                               int* __restrict__ rowptr, int* __restrict__ adj,
                                               int N, int NB) {
  __shared__ int ldeg[NPB];
  __shared__ int s[NPB];
  __shared__ int ladj[LCAP];
  __shared__ int o0s, cnts;
  const int b = blockIdx.x;
  const int tid = threadIdx.x;

  if (tid < 256) s[tid] = (tid < NB) ? (cursor[tid] - tid * BCAP) : 0;
  __syncthreads();
  for (int off = 1; off < 256; off <<= 1) {
    int t = 0;
    if (tid < 256 && tid >= off) t = s[tid - off];
    __syncthreads();
    if (tid < 256) s[tid] += t;
    __syncthreads();
  }
  if (tid == 0) {
    const int cb = cursor[b] - b * BCAP;
    o0s = s[b] - cb;
    cnts = cb;
    if (b == 0) rowptr[N] = s[NB - 1];
  }
  __syncthreads();
  const int o0 = o0s;
  const int cnt = cnts;
  const int r0 = b * BCAP;

  if (tid < NPB) ldeg[tid] = 0;
  __syncthreads();
  for (int i = tid; i < cnt; i += 1024)
    atomicAdd(&ldeg[rec[r0 + i] >> SRC_BITS], 1);
  __syncthreads();
  int v = 0;
  if (tid < NPB) { v = ldeg[tid]; s[tid] = v; }
  __syncthreads();
  for (int off = 1; off < NPB; off <<= 1) {
    int t = 0;
    if (tid < NPB && tid >= off) t = s[tid - off];
    __syncthreads();
    if (tid < NPB) s[tid] += t;
    __syncthreads();
  }
  if (tid < NPB) {
    const int excl = s[tid] - v;
    const int node = b * NPB + tid;
    if (node < N) rowptr[node] = o0 + excl;
    ldeg[tid] = excl;  // reuse as scatter cursor
  }
  __syncthreads();
  if (cnt <= LCAP) {
    for (int i = tid; i < cnt; i += 1024) {
      const unsigned r = rec[r0 + i];
      const int p = atomicAdd(&ldeg[r >> SRC_BITS], 1);
      ladj[p] = (int)(r & ((1u << SRC_BITS) - 1));
    }
    __syncthreads();
    for (int i = tid; i < cnt; i += 1024) adj[o0 + i] = ladj[i];
  } else {  // safety fallback (never expected)
    for (int i = tid; i < cnt; i += 1024) {
      const unsigned r = rec[r0 + i];
      const int p = atomicAdd(&ldeg[r >> SRC_BITS], 1);
      adj[o0 + p] = (int)(r & ((1u << SRC_BITS) - 1));
    }
  }
}

// ---------------- GAT layer 1 aggregate over list1 (x4 unroll) -------
__global__ void k_gat1(const unsigned short* __restrict__ h1, const float* __restrict__ as1,
                       const float* __restrict__ ad1, const int* __restrict__ rowptr,
                       const int* __restrict__ adj, const float* __restrict__ b1,
                       float* __restrict__ g, const int* __restrict__ list1,
                       const int* __restrict__ cnt) {
  const int w = threadIdx.x >> 6;
  const int l = threadIdx.x & 63;
  const int idx = blockIdx.x * 4 + w;
  if (idx >= cnt[1]) return;
  const int n = list1[idx];
  const int half = l >> 5;
  const int q = l & 31;       // channels 4q..4q+3
  const int head = q >> 4;
  const float adh = ad1[n * 2 + head];
  float a0 = 0.f, a1 = 0.f, a2 = 0.f, a3 = 0.f, dsum = 0.f;
  const int kb = rowptr[n], ke = rowptr[n + 1];
  const int kend = ke - 1;
  for (int k = kb + half; k < ke; k += 8) {
    const int e1 = k + 2, e2 = k + 4, e3 = k + 6;
    const int s0 = adj[k];
    const int s1 = adj[min(e1, kend)];
    const int s2 = adj[min(e2, kend)];
    const int s3 = adj[min(e3, kend)];
    const float x0 = as1[s0 * 2 + head] + adh;
    const float x1 = as1[s1 * 2 + head] + adh;
    const float x2 = as1[s2 * 2 + head] + adh;
    const float x3 = as1[s3 * 2 + head] + adh;
    const uint2 u0 = *(const uint2*)(h1 + (size_t)s0 * 128 + 4 * q);
    const uint2 u1 = *(const uint2*)(h1 + (size_t)s1 * 128 + 4 * q);
    const uint2 u2 = *(const uint2*)(h1 + (size_t)s2 * 128 + 4 * q);
    const uint2 u3 = *(const uint2*)(h1 + (size_t)s3 * 128 + 4 * q);
    const float w0 = __expf(leaky(x0));
    const float w1 = (e1 < ke) ? __expf(leaky(x1)) : 0.f;
    const float w2 = (e2 < ke) ? __expf(leaky(x2)) : 0.f;
    const float w3 = (e3 < ke) ? __expf(leaky(x3)) : 0.f;
    dsum += (w0 + w1) + (w2 + w3);
    a0 = fmaf(w0, __uint_as_float(u0.x << 16), a0);
    a1 = fmaf(w0, __uint_as_float(u0.x & 0xFFFF0000u), a1);
    a2 = fmaf(w0, __uint_as_float(u0.y << 16), a2);
    a3 = fmaf(w0, __uint_as_float(u0.y & 0xFFFF0000u), a3);
    a0 = fmaf(w1, __uint_as_float(u1.x << 16), a0);
    a1 = fmaf(w1, __uint_as_float(u1.x & 0xFFFF0000u), a1);
    a2 = fmaf(w1, __uint_as_float(u1.y << 16), a2);
    a3 = fmaf(w1, __uint_as_float(u1.y & 0xFFFF0000u), a3);
    a0 = fmaf(w2, __uint_as_float(u2.x << 16), a0);
    a1 = fmaf(w2, __uint_as_float(u2.x & 0xFFFF0000u), a1);
    a2 = fmaf(w2, __uint_as_float(u2.y << 16), a2);
    a3 = fmaf(w2, __uint_as_float(u2.y & 0xFFFF0000u), a3);
    a0 = fmaf(w3, __uint_as_float(u3.x << 16), a0);
    a1 = fmaf(w3, __uint_as_float(u3.x & 0xFFFF0000u), a1);
    a2 = fmaf(w3, __uint_as_float(u3.y << 16), a2);
    a3 = fmaf(w3, __uint_as_float(u3.y & 0xFFFF0000u), a3);
  }
  a0 += __shfl_xor(a0, 32, 64);
  a1 += __shfl_xor(a1, 32, 64);
  a2 += __shfl_xor(a2, 32, 64);
  a3 += __shfl_xor(a3, 32, 64);
  dsum += __shfl_xor(dsum, 32, 64);
  if (half == 0) {
    const float inv = 1.f / (dsum + 1e-16f);
    const float4 bv = *(const float4*)(b1 + 4 * q);
    float g0 = fmaf(a0, inv, bv.x);
    float g1 = fmaf(a1, inv, bv.y);
    float g2v = fmaf(a2, inv, bv.z);
    float g3 = fmaf(a3, inv, bv.w);
    g0 = g0 > 0.f ? g0 : expm1f(g0);
    g1 = g1 > 0.f ? g1 : expm1f(g1);
    g2v = g2v > 0.f ? g2v : expm1f(g2v);
    g3 = g3 > 0.f ? g3 : expm1f(g3);
    *(float4*)(g + (size_t)n * 128 + 4 * q) = make_float4(g0, g1, g2v, g3);
  }
}

// ---------------- GAT layer 2 linear over list1: h2 = g @ W2 (bf16 out)
__global__ void k_h2(const float* __restrict__ g, const float* __restrict__ W2,
                     const float* __restrict__ att_s, const float* __restrict__ att_d,
                     unsigned short* __restrict__ h2, float* __restrict__ a_s,
                     float* __restrict__ a_d, const int* __restrict__ list1,
                     const int* __restrict__ cnt) {
  const int cnt1 = cnt[1];
  const int base0 = blockIdx.x * 32;
  if (base0 >= cnt1) return;
  __shared__ __align__(16) float W2s[128 * 64];
  __shared__ __align__(16) float gs[2][128];
  __shared__ float part[2][64];
  for (int i = threadIdx.x; i < 128 * 64; i += 256) W2s[i] = W2[i];
  const int col = threadIdx.x & 63;
  const int kh  = (threadIdx.x >> 6) & 1;
  const int ln  = threadIdx.x >> 7;
  const float as_w = att_s[col], ad_w = att_d[col];
  __syncthreads();
  float wreg[64];
#pragma unroll
  for (int cc = 0; cc < 64; ++cc) wreg[cc] = W2s[(kh * 64 + cc) * 64 + col];

  for (int it = 0; it < 16; ++it) {
    const int sbase = base0 + it * 2;
    __syncthreads();
    {
      const int slot = sbase + (threadIdx.x >> 7);
      if (slot < cnt1) {
        const int nn = list1[slot];
        gs[threadIdx.x >> 7][threadIdx.x & 127] = g[(size_t)nn * 128 + (threadIdx.x & 127)];
      }
    }
    __syncthreads();
    const int slot = sbase + ln;
    const int n = (slot < cnt1) ? list1[slot] : -1;
    float acc = 0.f;
    if (n >= 0) {
#pragma unroll
      for (int q = 0; q < 16; ++q) {
        const float4 gv = *(const float4*)&gs[ln][kh * 64 + q * 4];
        acc = fmaf(gv.x, wreg[q * 4 + 0], acc);
        acc = fmaf(gv.y, wreg[q * 4 + 1], acc);
        acc = fmaf(gv.z, wreg[q * 4 + 2], acc);
        acc = fmaf(gv.w, wreg[q * 4 + 3], acc);
      }
    }
    if (kh == 1) part[ln][col] = acc;
    __syncthreads();
    if (kh == 0 && n >= 0) {
      acc += part[ln][col];
      h2[(size_t)n * 64 + col] = f2bf(acc);
      float vs = acc * as_w, vd = acc * ad_w;
#pragma unroll
      for (int off = 32; off > 0; off >>= 1) {
        vs += __shfl_down(vs, off, 64);
        vd += __shfl_down(vd, off, 64);
      }
      if (col == 0) { a_s[n] = vs; a_d[n] = vd; }
    }
  }
}

// ---------------- GAT layer 2 aggregate over listC (x4 unroll) ----------------
__global__ void k_gat2(const unsigned short* __restrict__ h2, const float* __restrict__ as2,
                       const float* __restrict__ ad2, const int* __restrict__ rowptr,
                       const int* __restrict__ adj, const float* __restrict__ b2,
                       float* __restrict__ g2, const int* __restrict__ listC,
                       const int* __restrict__ cnt) {
  const int w = threadIdx.x >> 6;
  const int l = threadIdx.x & 63;
  const int idx = blockIdx.x * 4 + w;
  if (idx >= cnt[0]) return;
  const int n = listC[idx];
  const int half = l >> 5;
  const int q = l & 31;       // channels 2q, 2q+1
  const float adh = ad2[n];
  float a0 = 0.f, a1 = 0.f, dsum = 0.f;
  const int kb = rowptr[n], ke = rowptr[n + 1];
  const int kend = ke - 1;
  for (int k = kb + half; k < ke; k += 8) {
    const int e1 = k + 2, e2 = k + 4, e3 = k + 6;
    const int s0 = adj[k];
    const int s1 = adj[min(e1, kend)];
    const int s2 = adj[min(e2, kend)];
    const int s3 = adj[min(e3, kend)];
    const float x0 = as2[s0] + adh;
    const float x1 = as2[s1] + adh;
    const float x2 = as2[s2] + adh;
    const float x3 = as2[s3] + adh;
    const unsigned u0 = *(const unsigned*)(h2 + (size_t)s0 * 64 + 2 * q);
    const unsigned u1 = *(const unsigned*)(h2 + (size_t)s1 * 64 + 2 * q);
    const unsigned u2 = *(const unsigned*)(h2 + (size_t)s2 * 64 + 2 * q);
    const unsigned u3 = *(const unsigned*)(h2 + (size_t)s3 * 64 + 2 * q);
    const float w0 = __expf(leaky(x0));
    const float w1 = (e1 < ke) ? __expf(leaky(x1)) : 0.f;
    const float w2 = (e2 < ke) ? __expf(leaky(x2)) : 0.f;
    const float w3 = (e3 < ke) ? __expf(leaky(x3)) : 0.f;
    dsum += (w0 + w1) + (w2 + w3);
    a0 = fmaf(w0, __uint_as_float(u0 << 16), a0);
    a1 = fmaf(w0, __uint_as_float(u0 & 0xFFFF0000u), a1);
    a0 = fmaf(w1, __uint_as_float(u1 << 16), a0);
    a1 = fmaf(w1, __uint_as_float(u1 & 0xFFFF0000u), a1);
    a0 = fmaf(w2, __uint_as_float(u2 << 16), a0);
    a1 = fmaf(w2, __uint_as_float(u2 & 0xFFFF0000u), a1);
    a0 = fmaf(w3, __uint_as_float(u3 << 16), a0);
    a1 = fmaf(w3, __uint_as_float(u3 & 0xFFFF0000u), a1);
  }
  a0 += __shfl_xor(a0, 32, 64);
  a1 += __shfl_xor(a1, 32, 64);
  dsum += __shfl_xor(dsum, 32, 64);
  if (half == 0) {
    const float inv = 1.f / (dsum + 1e-16f);
    const float2 bv = *(const float2*)(b2 + 2 * q);
    ((float2*)g2)[(size_t)n * 32 + q] =
        make_float2(fmaf(a0, inv, bv.x), fmaf(a1, inv, bv.y));
  }
}

// ---------------- build x matrix, bf16, K-blocked: xb[k/32][512][32] ----------------
__global__ void k_xmat(const int* __restrict__ user_idx, const int* __restrict__ ctx_idx,
                       const float* __restrict__ user_emb, const float* __restrict__ g2,
                       unsigned short* __restrict__ xb) {
  const int b = blockIdx.x;
  const int k = threadIdx.x;  // 0..255
  float v;
  if (k < 64) {
    v = user_emb[(size_t)user_idx[b] * 64 + k];
  } else {
    const int c = (k - 64) >> 6;
    v = g2[(size_t)ctx_idx[b * 3 + c] * 64 + (k & 63)];
  }
  xb[(size_t)(k >> 5) * (512 * 32) + b * 32 + (k & 31)] = f2bf(v);
}

// ---------------- final FC via MFMA: 1024 threads, 16 waves x 32 rows -------------
// Halved per-wave state (afr[2][8] = 64 VGPR, v[8]) -> ~2x resident waves per CU
// for load/stage/MFMA/store overlap. Same tiles, dbuf LDS, lgkm-only barriers.
__global__ __launch_bounds__(1024) void k_fc(const unsigned short* __restrict__ xb,
                                             const float* __restrict__ fc_w,
                                             const float* __restrict__ fc_b,
                                             float* __restrict__ out, int NSRV,
                                             int ntiles, int gstride) {
  __shared__ __align__(16) unsigned short Blds[2][32 * 264];  // 33 KB

  const int tid = threadIdx.x;
  const int w = tid >> 6;        // wave 0..15, owns rows [32w, 32w+32)
  const int lane = tid & 63;
  const int l15 = lane & 15;
  const int kg = lane >> 4;

  if (blockIdx.x >= (unsigned)ntiles) return;

  // persistent A fragments (MFMA B operand after the swap): 2 mf x 8 ks
  short8 afr[2][8];
#pragma unroll
  for (int mf = 0; mf < 2; ++mf) {
    const int row = w * 32 + mf * 16 + l15;
#pragma unroll
    for (int ks = 0; ks < 8; ++ks) {
      afr[mf][ks] = *(const short8*)(xb + (size_t)ks * 16384 + row * 32 + kg * 8);
    }
  }

  const int sc  = tid & 31;         // stage: col in tile
  const int sk0 = (tid >> 5) * 8;   // stage: contiguous k-chunk base (0,8,..,248)

  float v[8];
  auto loadv = [&](int t) {
    const int cg = t * 32 + sc;
    const bool okc = cg < NSRV;
#pragma unroll
    for (int i = 0; i < 8; ++i)
      v[i] = okc ? __builtin_nontemporal_load(fc_w + (size_t)(sk0 + i) * NSRV + cg) : 0.f;
  };
  auto writev = [&](int buf) {
    short8 lo;
#pragma unroll
    for (int i = 0; i < 8; ++i) lo[i] = (short)f2bf(v[i]);
    *(short8*)&Blds[buf][sc * 264 + sk0] = lo;
  };

  // prologue: tile t0 staged, loads for t0+gs in flight
  loadv(blockIdx.x);
  writev(0);
  if (blockIdx.x + gstride < ntiles) loadv(blockIdx.x + gstride);
  LGKM_BARRIER();

  int cur = 0;
  for (int t = blockIdx.x; t < ntiles; t += gstride) {
    if (t + gstride < ntiles) writev(cur ^ 1);   // consumes loads issued a tile ago
    if (t + 2 * gstride < ntiles) loadv(t + 2 * gstride);
    const int j0 = t * 32;
#pragma unroll
    for (int nf = 0; nf < 2; ++nf) {
      short8 bfr[8];
#pragma unroll
      for (int ks = 0; ks < 8; ++ks)
        bfr[ks] = *(const short8*)&Blds[cur][(nf * 16 + l15) * 264 + ks * 32 + kg * 8];
      f32x4 acc[2];
#pragma unroll
      for (int mf = 0; mf < 2; ++mf) acc[mf] = (f32x4){0.f, 0.f, 0.f, 0.f};
#pragma unroll
      for (int ks = 0; ks < 8; ++ks)
#pragma unroll
        for (int mf = 0; mf < 2; ++mf)
          acc[mf] = __builtin_amdgcn_mfma_f32_16x16x32_bf16(bfr[ks], afr[mf][ks], acc[mf], 0, 0, 0);
      const int jc = j0 + nf * 16 + kg * 4;
      if (j0 + 32 <= NSRV) {
        const float4 bias = *(const float4*)(fc_b + jc);
#pragma unroll
        for (int mf = 0; mf < 2; ++mf) {
          const int row = w * 32 + mf * 16 + l15;
          f32x4 o;
          o[0] = acc[mf][0] + bias.x;
          o[1] = acc[mf][1] + bias.y;
          o[2] = acc[mf][2] + bias.z;
          o[3] = acc[mf][3] + bias.w;
          __builtin_nontemporal_store(o, (f32x4*)(out + (size_t)row * NSRV + jc));
        }
      } else {
#pragma unroll
        for (int mf = 0; mf < 2; ++mf) {
          const int row = w * 32 + mf * 16 + l15;
#pragma unroll
          for (int r = 0; r < 4; ++r) {
            const int j = jc + r;
            if (j < NSRV) out[(size_t)row * NSRV + j] = acc[mf][r] + fc_b[j];
          }
        }
      }
    }
    LGKM_BARRIER();
    cur ^= 1;
  }
}

// =====================================================================
extern "C" void kernel_launch(void* const* d_in, const int* in_sizes, int n_in,
                              void* d_out, int out_size, void* d_ws, size_t ws_size,
                              hipStream_t stream) {
  const int* user_idx    = (const int*)d_in[0];
  const int* context_idx = (const int*)d_in[1];
  const int* edge_index  = (const int*)d_in[2];
  const float* user_emb  = (const float*)d_in[3];
  const float* service_emb = (const float*)d_in[4];
  const float* W1        = (const float*)d_in[5];
  const float* att_src1  = (const float*)d_in[6];
  const float* att_dst1  = (const float*)d_in[7];
  const float* b1        = (const float*)d_in[8];
  const float* W2        = (const float*)d_in[9];
  const float* att_src2  = (const float*)d_in[10];
  const float* att_dst2  = (const float*)d_in[11];
  const float* b2        = (const float*)d_in[12];
  const float* fc_w      = (const float*)d_in[13];
  const float* fc_b      = (const float*)d_in[14];
  float* out = (float*)d_out;

  const int B    = in_sizes[0];
  const int E    = in_sizes[2] / 2;
  const int N    = in_sizes[4] / 64;
  const int NSRV = in_sizes[14];
  const int Etot = E + N;
  const int NCTX = in_sizes[1];  // B*CTX
  (void)B;

  const int* edge_src = edge_index;
  const int* edge_dst = edge_index + E;

  // ---- workspace layout ----
  char* ws = (char*)d_ws;
  size_t off = 0;
  auto alloc = [&](size_t bytes) {
    void* p = ws + off;
    off = (off + bytes + 255) & ~(size_t)255;
    return p;
  };
  const int NB = (N + NPB - 1) >> NPB_SH;   // 196 for N=100000 (requires <=256)
  unsigned short* h1 = (unsigned short*)alloc((size_t)N * 128 * 2);  // reused as h2
  float* g      = (float*)alloc((size_t)N * 128 * 4);                // reused as g2
  float* as1    = (float*)alloc((size_t)N * 2 * 4);
  float* ad1    = (float*)alloc((size_t)N * 2 * 4);
  float* as2    = (float*)alloc((size_t)N * 4);
  float* ad2    = (float*)alloc((size_t)N * 4);
  int*   rowptr = (int*)alloc((size_t)(N + 1) * 4);
  int*   adj    = (int*)alloc((size_t)Etot * 4);
  unsigned* rec = (unsigned*)alloc((size_t)NB * BCAP * 4);
  int* bucketCursor = (int*)alloc(256 * 4);
  int* flagC  = (int*)alloc((size_t)N * 4);
  int* flag1  = (int*)alloc((size_t)N * 4);
  int* listC  = (int*)alloc((size_t)NCTX * 4);
  int* list1  = (int*)alloc((size_t)N * 4);
  int* cnt    = (int*)alloc(2 * 4);
  unsigned short* xb = (unsigned short*)alloc((size_t)512 * 256 * 2);
  unsigned short* h2 = h1;
  float* g2 = g;
  (void)ws_size;

  const int NBLK2 = 256;
  const int epb = (Etot + NBLK2 - 1) / NBLK2;
  const int nblk_N = (N + 255) / 256;
  const int nblk_E = (Etot + 255) / 256;

  // combined init (bucket cursors + frontier flags)
  k_init<<<nblk_N, 256, 0, stream>>>(bucketCursor, NB, flagC, flag1, cnt, N);

  // GAT layer 1 linear (full N — sources cover ~99% of nodes)
  k_h1<<<(N + 31) / 32, 256, 0, stream>>>(service_emb, W1, att_src1, att_dst1, h1, as1, ad1, N);

  // frontier: plain-store marking, then block-compaction (no hot atomics)
  k_markC<<<(NCTX + 255) / 256, 256, 0, stream>>>(context_idx, NCTX, flagC, flag1);
  k_markS1e<<<nblk_E, 256, 0, stream>>>(edge_src, edge_dst, E, Etot, flagC, flag1);
  k_compact<<<nblk_N, 256, 0, stream>>>(flagC, flag1, listC, list1, cnt, N);

  // CSR build, FILTERED to edges with dst in S1 (~27% of edges)
  k_bscatter<<<NBLK2, 1024, 0, stream>>>(edge_src, edge_dst, E, Etot, epb, flag1, bucketCursor, rec, NB);
  k_bcsr<<<NB, 1024, 0, stream>>>(rec, bucketCursor, rowptr, adj, N, NB);

  // layer 1 aggregate -> g (elu'd), only for list1 nodes
  k_gat1<<<(N + 3) / 4, 256, 0, stream>>>(h1, as1, ad1, rowptr, adj, b1, g, list1, cnt);

  // layer 2 linear (h2 overlays h1), only for list1 nodes
  k_h2<<<(N + 31) / 32, 256, 0, stream>>>(g, W2, att_src2, att_dst2, h2, as2, ad2, list1, cnt);

  // layer 2 aggregate -> g2 (overlays g), only for C nodes
  k_gat2<<<(NCTX + 3) / 4, 256, 0, stream>>>(h2, as2, ad2, rowptr, adj, b2, g2, listC, cnt);

  // gather features -> bf16 K-blocked
  k_xmat<<<512, 256, 0, stream>>>(user_idx, context_idx, user_emb, g2, xb);

  // final FC (MFMA, 16 waves x 32 rows, double-buffered 32-col grid-strided tiles)
  const int nfct = (NSRV + 31) / 32;
  const int grid = 512;
  k_fc<<<grid, 1024, 0, stream>>>(xb, fc_w, fc_b, out, NSRV, nfct, grid);
}

// Round 18
// 261.630 us; speedup vs baseline: 1.0706x; 1.0626x over previous
//
#include <hip/hip_runtime.h>
#include <hip/hip_bf16.h>
#include <math.h>

#define NEG_SLOPE 0.2f

// CSR binning parameters (N=100000, E+N~1.7M; requires N < 2^18 and NB <= 256)
#define NPB 512       // nodes per bucket
#define NPB_SH 9
#define SRC_BITS 18
#define LCAP 16384    // LDS adj staging capacity (edges) per bucket
#define BCAP 16384    // fixed per-bucket record capacity (filtered mean ~2.4K)

typedef __attribute__((ext_vector_type(8))) short short8;
typedef __attribute__((ext_vector_type(4))) float f32x4;

__device__ __forceinline__ float leaky(float x) { return x > 0.f ? x : NEG_SLOPE * x; }

__device__ __forceinline__ unsigned short f2bf(float f) {
  unsigned u = __float_as_uint(f);
  unsigned r = (u + 0x7FFFu + ((u >> 16) & 1u)) >> 16;  // RNE
  return (unsigned short)r;
}

// LDS-only barrier: orders ds ops across waves without draining global loads/stores.
#define LGKM_BARRIER()                                   \
  do {                                                   \
    asm volatile("s_waitcnt lgkmcnt(0)" ::: "memory");   \
    __builtin_amdgcn_s_barrier();                        \
  } while (0)

// ---------------- GAT layer 1 linear + fused init ----------------
// h1[N,128] = x[N,64] @ W1[64,128] (bf16 out). Blocks < 391 also zero the
// frontier flags / bucket cursors / counters (disjoint buffers, consumers later).
__global__ void k_h1(const float* __restrict__ x, const float* __restrict__ W1,
                     const float* __restrict__ att_src, const float* __restrict__ att_dst,
                     unsigned short* __restrict__ h1, float* __restrict__ a_s,
                     float* __restrict__ a_d, int N,
                     int* __restrict__ cursor, int NB, int* __restrict__ flagC,
                     int* __restrict__ flag1, int* __restrict__ cnt) {
  const int tid = threadIdx.x;
  const int gi = blockIdx.x * 256 + tid;
  if (gi < N) { flagC[gi] = 0; flag1[gi] = 0; }
  if (gi < NB) cursor[gi] = gi * BCAP;
  if (gi < 2) cnt[gi] = 0;

  __shared__ __align__(16) float W1s[64 * 128];   // 32 KB
  __shared__ __align__(16) float xs[32][64];      // 8 KB
  for (int i = tid; i < 64 * 128; i += 256) W1s[i] = W1[i];
  const int node0 = blockIdx.x * 32;
  for (int i = tid; i < 512; i += 256) {
    const int nn = node0 + (i >> 4);
    if (nn < N) ((float4*)xs)[i] = *(const float4*)(x + (size_t)nn * 64 + (i & 15) * 4);
  }
  const int ln  = tid >> 7;   // node slot 0/1
  const int col = tid & 127;  // output channel
  const int head = col >> 6;
  const int c = col & 63;
  const float as_w = att_src[head * 64 + c];
  const float ad_w = att_dst[head * 64 + c];
  __syncthreads();  // W1s + xs ready
  float wreg[64];
#pragma unroll
  for (int cc = 0; cc < 64; ++cc) wreg[cc] = W1s[cc * 128 + col];

  for (int it = 0; it < 16; ++it) {
    const int slot = it * 2 + ln;
    const int n = node0 + slot;
    if (n >= N) continue;
    float acc = 0.f;
#pragma unroll
    for (int q = 0; q < 16; ++q) {
      const float4 xv = *(const float4*)&xs[slot][q * 4];
      acc = fmaf(xv.x, wreg[q * 4 + 0], acc);
      acc = fmaf(xv.y, wreg[q * 4 + 1], acc);
      acc = fmaf(xv.z, wreg[q * 4 + 2], acc);
      acc = fmaf(xv.w, wreg[q * 4 + 3], acc);
    }
    h1[(size_t)n * 128 + col] = f2bf(acc);
    float vs = acc * as_w;
    float vd = acc * ad_w;
#pragma unroll
    for (int off = 32; off > 0; off >>= 1) {
      vs += __shfl_down(vs, off, 64);
      vd += __shfl_down(vd, off, 64);
    }
    if (c == 0) { a_s[n * 2 + head] = vs; a_d[n * 2 + head] = vd; }
  }
}

// ---------------- demand-driven frontier: plain-store marking (no atomics) ----------
__global__ void k_markC(const int* __restrict__ ctx, int nctx, int* __restrict__ flagC,
                        int* __restrict__ flag1) {
  const int i = blockIdx.x * 256 + threadIdx.x;
  if (i >= nctx) return;
  const int n = ctx[i];
  flagC[n] = 1;   // idempotent
  flag1[n] = 1;
}

// edge-scan: flag1 |= {src[e] : dst[e] ∈ C}. Plain stores, fire-and-forget.
__global__ void k_markS1e(const int* __restrict__ src, const int* __restrict__ dst,
                          int E, int Etot, const int* __restrict__ flagC,
                          int* __restrict__ flag1) {
  const int e = blockIdx.x * 256 + threadIdx.x;
  if (e >= Etot) return;
  int s, d;
  if (e < E) { s = src[e]; d = dst[e]; } else { s = d = e - E; }
  if (flagC[d]) flag1[s] = 1;
}

// ---------------- fused: flag compaction + filtered bucket scatter ----------------
// Blocks [0, nblkC): compact flags -> lists (1 global atomic per block per list).
// Blocks [nblkC, nblkC+NBLK2): chunk-reserved scatter of filtered edge records.
__global__ __launch_bounds__(1024) void k_front(
    const int* __restrict__ flagC, const int* __restrict__ flag1,
    int* __restrict__ listC, int* __restrict__ list1, int* __restrict__ cnt,
    int N, int nblkC,
    const int* __restrict__ src, const int* __restrict__ dst, int E, int Etot,
    int epb, int* __restrict__ cursor, unsigned* __restrict__ rec, int NB) {
  __shared__ int hist[256];
  __shared__ int cur[256];
  const int tid = threadIdx.x;

  if ((int)blockIdx.x < nblkC) {
    // ---- compaction ----
    const int i = blockIdx.x * 1024 + tid;
    if (tid == 0) { hist[0] = 0; hist[1] = 0; }
    __syncthreads();
    int pc = -1, p1 = -1;
    if (i < N) {
      if (flagC[i]) pc = atomicAdd(&hist[0], 1);
      if (flag1[i]) p1 = atomicAdd(&hist[1], 1);
    }
    __syncthreads();
    if (tid == 0) {
      cur[0] = hist[0] ? atomicAdd(&cnt[0], hist[0]) : 0;
      cur[1] = hist[1] ? atomicAdd(&cnt[1], hist[1]) : 0;
    }
    __syncthreads();
    if (pc >= 0) listC[cur[0] + pc] = i;
    if (p1 >= 0) list1[cur[1] + p1] = i;
    return;
  }

  // ---- filtered bucket scatter ----
  const int bb = blockIdx.x - nblkC;
  if (tid < 256) hist[tid] = 0;
  __syncthreads();
  const int e0 = bb * epb;
  const int e1 = min(e0 + epb, Etot);
  for (int e = e0 + tid; e < e1; e += 1024) {
    const int d = (e < E) ? dst[e] : (e - E);
    if (flag1[d]) atomicAdd(&hist[d >> NPB_SH], 1);
  }
  __syncthreads();
  if (tid < NB) {
    const int c = hist[tid];
    cur[tid] = c ? atomicAdd(&cursor[tid], c) : 0;
  }
  __syncthreads();
  for (int e = e0 + tid; e < e1; e += 1024) {
    int sv, d;
    if (e < E) { sv = src[e]; d = dst[e]; } else { sv = d = e - E; }
    if (!flag1[d]) continue;
    const int b = d >> NPB_SH;
    const int p = atomicAdd(&cur[b], 1);
    rec[p] = (unsigned)sv | ((unsigned)(d & (NPB - 1)) << SRC_BITS);
  }
}

// one block per bucket: recompute bucket prefix from cursor deltas, then local
// degree count, scan, LDS scatter, coalesced copy out.
__global__ __launch_bounds__(1024) void k_bcsr(const unsigned* __restrict__ rec,
                                               const int* __restrict__ cursor,
                                               int* __restrict__ rowptr, int* __restrict__ adj,
                                               int N, int NB) {
  __shared__ int ldeg[NPB];
  __shared__ int s[NPB];
  __shared__ int ladj[LCAP];
  __shared__ int o0s, cnts;
  const int b = blockIdx.x;
  const int tid = threadIdx.x;

  if (tid < 256) s[tid] = (tid < NB) ? (cursor[tid] - tid * BCAP) : 0;
  __syncthreads();
  for (int off = 1; off < 256; off <<= 1) {
    int t = 0;
    if (tid < 256 && tid >= off) t = s[tid - off];
    __syncthreads();
    if (tid < 256) s[tid] += t;
    __syncthreads();
  }
  if (tid == 0) {
    const int cb = cursor[b] - b * BCAP;
    o0s = s[b] - cb;
    cnts = cb;
    if (b == 0) rowptr[N] = s[NB - 1];
  }
  __syncthreads();
  const int o0 = o0s;
  const int cnt = cnts;
  const int r0 = b * BCAP;

  if (tid < NPB) ldeg[tid] = 0;
  __syncthreads();
  for (int i = tid; i < cnt; i += 1024)
    atomicAdd(&ldeg[rec[r0 + i] >> SRC_BITS], 1);
  __syncthreads();
  int v = 0;
  if (tid < NPB) { v = ldeg[tid]; s[tid] = v; }
  __syncthreads();
  for (int off = 1; off < NPB; off <<= 1) {
    int t = 0;
    if (tid < NPB && tid >= off) t = s[tid - off];
    __syncthreads();
    if (tid < NPB) s[tid] += t;
    __syncthreads();
  }
  if (tid < NPB) {
    const int excl = s[tid] - v;
    const int node = b * NPB + tid;
    if (node < N) rowptr[node] = o0 + excl;
    ldeg[tid] = excl;  // reuse as scatter cursor
  }
  __syncthreads();
  if (cnt <= LCAP) {
    for (int i = tid; i < cnt; i += 1024) {
      const unsigned r = rec[r0 + i];
      const int p = atomicAdd(&ldeg[r >> SRC_BITS], 1);
      ladj[p] = (int)(r & ((1u << SRC_BITS) - 1));
    }
    __syncthreads();
    for (int i = tid; i < cnt; i += 1024) adj[o0 + i] = ladj[i];
  } else {  // safety fallback (never expected)
    for (int i = tid; i < cnt; i += 1024) {
      const unsigned r = rec[r0 + i];
      const int p = atomicAdd(&ldeg[r >> SRC_BITS], 1);
      adj[o0 + p] = (int)(r & ((1u << SRC_BITS) - 1));
    }
  }
}

// ---------------- GAT layer 1 aggregate over list1 (grid-strided, x4 unroll) -------
__global__ void k_gat1(const unsigned short* __restrict__ h1, const float* __restrict__ as1,
                       const float* __restrict__ ad1, const int* __restrict__ rowptr,
                       const int* __restrict__ adj, const float* __restrict__ b1,
                       float* __restrict__ g, const int* __restrict__ list1,
                       const int* __restrict__ cnt, int gspan) {
  const int w = threadIdx.x >> 6;
  const int l = threadIdx.x & 63;
  const int half = l >> 5;
  const int q = l & 31;       // channels 4q..4q+3
  const int head = q >> 4;
  const int cnt1 = cnt[1];
  for (int idx = blockIdx.x * 4 + w; idx < cnt1; idx += gspan) {
    const int n = list1[idx];
    const float adh = ad1[n * 2 + head];
    float a0 = 0.f, a1 = 0.f, a2 = 0.f, a3 = 0.f, dsum = 0.f;
    const int kb = rowptr[n], ke = rowptr[n + 1];
    const int kend = ke - 1;
    for (int k = kb + half; k < ke; k += 8) {
      const int e1 = k + 2, e2 = k + 4, e3 = k + 6;
      const int s0 = adj[k];
      const int s1 = adj[min(e1, kend)];
      const int s2 = adj[min(e2, kend)];
      const int s3 = adj[min(e3, kend)];
      const float x0 = as1[s0 * 2 + head] + adh;
      const float x1 = as1[s1 * 2 + head] + adh;
      const float x2 = as1[s2 * 2 + head] + adh;
      const float x3 = as1[s3 * 2 + head] + adh;
      const uint2 u0 = *(const uint2*)(h1 + (size_t)s0 * 128 + 4 * q);
      const uint2 u1 = *(const uint2*)(h1 + (size_t)s1 * 128 + 4 * q);
      const uint2 u2 = *(const uint2*)(h1 + (size_t)s2 * 128 + 4 * q);
      const uint2 u3 = *(const uint2*)(h1 + (size_t)s3 * 128 + 4 * q);
      const float w0 = __expf(leaky(x0));
      const float w1 = (e1 < ke) ? __expf(leaky(x1)) : 0.f;
      const float w2 = (e2 < ke) ? __expf(leaky(x2)) : 0.f;
      const float w3 = (e3 < ke) ? __expf(leaky(x3)) : 0.f;
      dsum += (w0 + w1) + (w2 + w3);
      a0 = fmaf(w0, __uint_as_float(u0.x << 16), a0);
      a1 = fmaf(w0, __uint_as_float(u0.x & 0xFFFF0000u), a1);
      a2 = fmaf(w0, __uint_as_float(u0.y << 16), a2);
      a3 = fmaf(w0, __uint_as_float(u0.y & 0xFFFF0000u), a3);
      a0 = fmaf(w1, __uint_as_float(u1.x << 16), a0);
      a1 = fmaf(w1, __uint_as_float(u1.x & 0xFFFF0000u), a1);
      a2 = fmaf(w1, __uint_as_float(u1.y << 16), a2);
      a3 = fmaf(w1, __uint_as_float(u1.y & 0xFFFF0000u), a3);
      a0 = fmaf(w2, __uint_as_float(u2.x << 16), a0);
      a1 = fmaf(w2, __uint_as_float(u2.x & 0xFFFF0000u), a1);
      a2 = fmaf(w2, __uint_as_float(u2.y << 16), a2);
      a3 = fmaf(w2, __uint_as_float(u2.y & 0xFFFF0000u), a3);
      a0 = fmaf(w3, __uint_as_float(u3.x << 16), a0);
      a1 = fmaf(w3, __uint_as_float(u3.x & 0xFFFF0000u), a1);
      a2 = fmaf(w3, __uint_as_float(u3.y << 16), a2);
      a3 = fmaf(w3, __uint_as_float(u3.y & 0xFFFF0000u), a3);
    }
    a0 += __shfl_xor(a0, 32, 64);
    a1 += __shfl_xor(a1, 32, 64);
    a2 += __shfl_xor(a2, 32, 64);
    a3 += __shfl_xor(a3, 32, 64);
    dsum += __shfl_xor(dsum, 32, 64);
    if (half == 0) {
      const float inv = 1.f / (dsum + 1e-16f);
      const float4 bv = *(const float4*)(b1 + 4 * q);
      float g0 = fmaf(a0, inv, bv.x);
      float g1 = fmaf(a1, inv, bv.y);
      float g2v = fmaf(a2, inv, bv.z);
      float g3 = fmaf(a3, inv, bv.w);
      g0 = g0 > 0.f ? g0 : expm1f(g0);
      g1 = g1 > 0.f ? g1 : expm1f(g1);
      g2v = g2v > 0.f ? g2v : expm1f(g2v);
      g3 = g3 > 0.f ? g3 : expm1f(g3);
      *(float4*)(g + (size_t)n * 128 + 4 * q) = make_float4(g0, g1, g2v, g3);
    }
  }
}

// ---------------- GAT layer 2 linear over list1 (grid-strided): h2 = g @ W2 --------
__global__ void k_h2(const float* __restrict__ g, const float* __restrict__ W2,
                     const float* __restrict__ att_s, const float* __restrict__ att_d,
                     unsigned short* __restrict__ h2, float* __restrict__ a_s,
                     float* __restrict__ a_d, const int* __restrict__ list1,
                     const int* __restrict__ cnt) {
  const int cnt1 = cnt[1];
  __shared__ __align__(16) float W2s[128 * 64];
  __shared__ __align__(16) float gs[2][128];
  __shared__ float part[2][64];
  for (int i = threadIdx.x; i < 128 * 64; i += 256) W2s[i] = W2[i];
  const int col = threadIdx.x & 63;
  const int kh  = (threadIdx.x >> 6) & 1;
  const int ln  = threadIdx.x >> 7;
  const float as_w = att_s[col], ad_w = att_d[col];
  __syncthreads();
  float wreg[64];
#pragma unroll
  for (int cc = 0; cc < 64; ++cc) wreg[cc] = W2s[(kh * 64 + cc) * 64 + col];

  for (int base0 = blockIdx.x * 32; base0 < cnt1; base0 += gridDim.x * 32) {
    for (int it = 0; it < 16; ++it) {
      const int sbase = base0 + it * 2;
      __syncthreads();
      {
        const int slot = sbase + (threadIdx.x >> 7);
        if (slot < cnt1) {
          const int nn = list1[slot];
          gs[threadIdx.x >> 7][threadIdx.x & 127] = g[(size_t)nn * 128 + (threadIdx.x & 127)];
        }
      }
      __syncthreads();
      const int slot = sbase + ln;
      const int n = (slot < cnt1) ? list1[slot] : -1;
      float acc = 0.f;
      if (n >= 0) {
#pragma unroll
        for (int q = 0; q < 16; ++q) {
          const float4 gv = *(const float4*)&gs[ln][kh * 64 + q * 4];
          acc = fmaf(gv.x, wreg[q * 4 + 0], acc);
          acc = fmaf(gv.y, wreg[q * 4 + 1], acc);
          acc = fmaf(gv.z, wreg[q * 4 + 2], acc);
          acc = fmaf(gv.w, wreg[q * 4 + 3], acc);
        }
      }
      if (kh == 1) part[ln][col] = acc;
      __syncthreads();
      if (kh == 0 && n >= 0) {
        acc += part[ln][col];
        h2[(size_t)n * 64 + col] = f2bf(acc);
        float vs = acc * as_w, vd = acc * ad_w;
#pragma unroll
        for (int off = 32; off > 0; off >>= 1) {
          vs += __shfl_down(vs, off, 64);
          vd += __shfl_down(vd, off, 64);
        }
        if (col == 0) { a_s[n] = vs; a_d[n] = vd; }
      }
    }
  }
}

// ---------------- GAT layer 2 aggregate over listC (x4 unroll) ----------------
__global__ void k_gat2(const unsigned short* __restrict__ h2, const float* __restrict__ as2,
                       const float* __restrict__ ad2, const int* __restrict__ rowptr,
                       const int* __restrict__ adj, const float* __restrict__ b2,
                       float* __restrict__ g2, const int* __restrict__ listC,
                       const int* __restrict__ cnt) {
  const int w = threadIdx.x >> 6;
  const int l = threadIdx.x & 63;
  const int idx = blockIdx.x * 4 + w;
  if (idx >= cnt[0]) return;
  const int n = listC[idx];
  const int half = l >> 5;
  const int q = l & 31;       // channels 2q, 2q+1
  const float adh = ad2[n];
  float a0 = 0.f, a1 = 0.f, dsum = 0.f;
  const int kb = rowptr[n], ke = rowptr[n + 1];
  const int kend = ke - 1;
  for (int k = kb + half; k < ke; k += 8) {
    const int e1 = k + 2, e2 = k + 4, e3 = k + 6;
    const int s0 = adj[k];
    const int s1 = adj[min(e1, kend)];
    const int s2 = adj[min(e2, kend)];
    const int s3 = adj[min(e3, kend)];
    const float x0 = as2[s0] + adh;
    const float x1 = as2[s1] + adh;
    const float x2 = as2[s2] + adh;
    const float x3 = as2[s3] + adh;
    const unsigned u0 = *(const unsigned*)(h2 + (size_t)s0 * 64 + 2 * q);
    const unsigned u1 = *(const unsigned*)(h2 + (size_t)s1 * 64 + 2 * q);
    const unsigned u2 = *(const unsigned*)(h2 + (size_t)s2 * 64 + 2 * q);
    const unsigned u3 = *(const unsigned*)(h2 + (size_t)s3 * 64 + 2 * q);
    const float w0 = __expf(leaky(x0));
    const float w1 = (e1 < ke) ? __expf(leaky(x1)) : 0.f;
    const float w2 = (e2 < ke) ? __expf(leaky(x2)) : 0.f;
    const float w3 = (e3 < ke) ? __expf(leaky(x3)) : 0.f;
    dsum += (w0 + w1) + (w2 + w3);
    a0 = fmaf(w0, __uint_as_float(u0 << 16), a0);
    a1 = fmaf(w0, __uint_as_float(u0 & 0xFFFF0000u), a1);
    a0 = fmaf(w1, __uint_as_float(u1 << 16), a0);
    a1 = fmaf(w1, __uint_as_float(u1 & 0xFFFF0000u), a1);
    a0 = fmaf(w2, __uint_as_float(u2 << 16), a0);
    a1 = fmaf(w2, __uint_as_float(u2 & 0xFFFF0000u), a1);
    a0 = fmaf(w3, __uint_as_float(u3 << 16), a0);
    a1 = fmaf(w3, __uint_as_float(u3 & 0xFFFF0000u), a1);
  }
  a0 += __shfl_xor(a0, 32, 64);
  a1 += __shfl_xor(a1, 32, 64);
  dsum += __shfl_xor(dsum, 32, 64);
  if (half == 0) {
    const float inv = 1.f / (dsum + 1e-16f);
    const float2 bv = *(const float2*)(b2 + 2 * q);
    ((float2*)g2)[(size_t)n * 32 + q] =
        make_float2(fmaf(a0, inv, bv.x), fmaf(a1, inv, bv.y));
  }
}

// ---------------- build x matrix, bf16, K-blocked: xb[k/32][512][32] ----------------
__global__ void k_xmat(const int* __restrict__ user_idx, const int* __restrict__ ctx_idx,
                       const float* __restrict__ user_emb, const float* __restrict__ g2,
                       unsigned short* __restrict__ xb) {
  const int b = blockIdx.x;
  const int k = threadIdx.x;  // 0..255
  float v;
  if (k < 64) {
    v = user_emb[(size_t)user_idx[b] * 64 + k];
  } else {
    const int c = (k - 64) >> 6;
    v = g2[(size_t)ctx_idx[b * 3 + c] * 64 + (k & 63)];
  }
  xb[(size_t)(k >> 5) * (512 * 32) + b * 32 + (k & 31)] = f2bf(v);
}

// ---------------- final FC via MFMA: 1024 threads, 16 waves x 32 rows -------------
__global__ __launch_bounds__(1024) void k_fc(const unsigned short* __restrict__ xb,
                                             const float* __restrict__ fc_w,
                                             const float* __restrict__ fc_b,
                                             float* __restrict__ out, int NSRV,
                                             int ntiles, int gstride) {
  __shared__ __align__(16) unsigned short Blds[2][32 * 264];  // 33 KB

  const int tid = threadIdx.x;
  const int w = tid >> 6;        // wave 0..15, owns rows [32w, 32w+32)
  const int lane = tid & 63;
  const int l15 = lane & 15;
  const int kg = lane >> 4;

  if (blockIdx.x >= (unsigned)ntiles) return;

  // persistent A fragments (MFMA B operand after the swap): 2 mf x 8 ks
  short8 afr[2][8];
#pragma unroll
  for (int mf = 0; mf < 2; ++mf) {
    const int row = w * 32 + mf * 16 + l15;
#pragma unroll
    for (int ks = 0; ks < 8; ++ks) {
      afr[mf][ks] = *(const short8*)(xb + (size_t)ks * 16384 + row * 32 + kg * 8);
    }
  }

  const int sc  = tid & 31;         // stage: col in tile
  const int sk0 = (tid >> 5) * 8;   // stage: contiguous k-chunk base (0,8,..,248)

  float v[8];
  auto loadv = [&](int t) {
    const int cg = t * 32 + sc;
    const bool okc = cg < NSRV;
#pragma unroll
    for (int i = 0; i < 8; ++i)
      v[i] = okc ? __builtin_nontemporal_load(fc_w + (size_t)(sk0 + i) * NSRV + cg) : 0.f;
  };
  auto writev = [&](int buf) {
    short8 lo;
#pragma unroll
    for (int i = 0; i < 8; ++i) lo[i] = (short)f2bf(v[i]);
    *(short8*)&Blds[buf][sc * 264 + sk0] = lo;
  };

  // prologue: tile t0 staged, loads for t0+gs in flight
  loadv(blockIdx.x);
  writev(0);
  if (blockIdx.x + gstride < ntiles) loadv(blockIdx.x + gstride);
  LGKM_BARRIER();

  int cur = 0;
  for (int t = blockIdx.x; t < ntiles; t += gstride) {
    if (t + gstride < ntiles) writev(cur ^ 1);   // consumes loads issued a tile ago
    if (t + 2 * gstride < ntiles) loadv(t + 2 * gstride);
    const int j0 = t * 32;
#pragma unroll
    for (int nf = 0; nf < 2; ++nf) {
      short8 bfr[8];
#pragma unroll
      for (int ks = 0; ks < 8; ++ks)
        bfr[ks] = *(const short8*)&Blds[cur][(nf * 16 + l15) * 264 + ks * 32 + kg * 8];
      f32x4 acc[2];
#pragma unroll
      for (int mf = 0; mf < 2; ++mf) acc[mf] = (f32x4){0.f, 0.f, 0.f, 0.f};
#pragma unroll
      for (int ks = 0; ks < 8; ++ks)
#pragma unroll
        for (int mf = 0; mf < 2; ++mf)
          acc[mf] = __builtin_amdgcn_mfma_f32_16x16x32_bf16(bfr[ks], afr[mf][ks], acc[mf], 0, 0, 0);
      const int jc = j0 + nf * 16 + kg * 4;
      if (j0 + 32 <= NSRV) {
        const float4 bias = *(const float4*)(fc_b + jc);
#pragma unroll
        for (int mf = 0; mf < 2; ++mf) {
          const int row = w * 32 + mf * 16 + l15;
          f32x4 o;
          o[0] = acc[mf][0] + bias.x;
          o[1] = acc[mf][1] + bias.y;
          o[2] = acc[mf][2] + bias.z;
          o[3] = acc[mf][3] + bias.w;
          __builtin_nontemporal_store(o, (f32x4*)(out + (size_t)row * NSRV + jc));
        }
      } else {
#pragma unroll
        for (int mf = 0; mf < 2; ++mf) {
          const int row = w * 32 + mf * 16 + l15;
#pragma unroll
          for (int r = 0; r < 4; ++r) {
            const int j = jc + r;
            if (j < NSRV) out[(size_t)row * NSRV + j] = acc[mf][r] + fc_b[j];
          }
        }
      }
    }
    LGKM_BARRIER();
    cur ^= 1;
  }
}

// =====================================================================
extern "C" void kernel_launch(void* const* d_in, const int* in_sizes, int n_in,
                              void* d_out, int out_size, void* d_ws, size_t ws_size,
                              hipStream_t stream) {
  const int* user_idx    = (const int*)d_in[0];
  const int* context_idx = (const int*)d_in[1];
  const int* edge_index  = (const int*)d_in[2];
  const float* user_emb  = (const float*)d_in[3];
  const float* service_emb = (const float*)d_in[4];
  const float* W1        = (const float*)d_in[5];
  const float* att_src1  = (const float*)d_in[6];
  const float* att_dst1  = (const float*)d_in[7];
  const float* b1        = (const float*)d_in[8];
  const float* W2        = (const float*)d_in[9];
  const float* att_src2  = (const float*)d_in[10];
  const float* att_dst2  = (const float*)d_in[11];
  const float* b2        = (const float*)d_in[12];
  const float* fc_w      = (const float*)d_in[13];
  const float* fc_b      = (const float*)d_in[14];
  float* out = (float*)d_out;

  const int B    = in_sizes[0];
  const int E    = in_sizes[2] / 2;
  const int N    = in_sizes[4] / 64;
  const int NSRV = in_sizes[14];
  const int Etot = E + N;
  const int NCTX = in_sizes[1];  // B*CTX
  (void)B;

  const int* edge_src = edge_index;
  const int* edge_dst = edge_index + E;

  // ---- workspace layout ----
  char* ws = (char*)d_ws;
  size_t off = 0;
  auto alloc = [&](size_t bytes) {
    void* p = ws + off;
    off = (off + bytes + 255) & ~(size_t)255;
    return p;
  };
  const int NB = (N + NPB - 1) >> NPB_SH;   // 196 for N=100000 (requires <=256)
  unsigned short* h1 = (unsigned short*)alloc((size_t)N * 128 * 2);  // reused as h2
  float* g      = (float*)alloc((size_t)N * 128 * 4);                // reused as g2
  float* as1    = (float*)alloc((size_t)N * 2 * 4);
  float* ad1    = (float*)alloc((size_t)N * 2 * 4);
  float* as2    = (float*)alloc((size_t)N * 4);
  float* ad2    = (float*)alloc((size_t)N * 4);
  int*   rowptr = (int*)alloc((size_t)(N + 1) * 4);
  int*   adj    = (int*)alloc((size_t)Etot * 4);
  unsigned* rec = (unsigned*)alloc((size_t)NB * BCAP * 4);
  int* bucketCursor = (int*)alloc(256 * 4);
  int* flagC  = (int*)alloc((size_t)N * 4);
  int* flag1  = (int*)alloc((size_t)N * 4);
  int* listC  = (int*)alloc((size_t)NCTX * 4);
  int* list1  = (int*)alloc((size_t)N * 4);
  int* cnt    = (int*)alloc(2 * 4);
  unsigned short* xb = (unsigned short*)alloc((size_t)512 * 256 * 2);
  unsigned short* h2 = h1;
  float* g2 = g;
  (void)ws_size;

  const int NBLK2 = 256;
  const int epb = (Etot + NBLK2 - 1) / NBLK2;
  const int nblk_E = (Etot + 255) / 256;
  const int nblkC = (N + 1023) / 1024;   // compaction blocks (1024 thr)

  // GAT layer 1 linear + fused init (flags/cursors/counters)
  k_h1<<<(N + 31) / 32, 256, 0, stream>>>(service_emb, W1, att_src1, att_dst1, h1, as1, ad1, N,
                                          bucketCursor, NB, flagC, flag1, cnt);

  // frontier: plain-store marking
  k_markC<<<(NCTX + 255) / 256, 256, 0, stream>>>(context_idx, NCTX, flagC, flag1);
  k_markS1e<<<nblk_E, 256, 0, stream>>>(edge_src, edge_dst, E, Etot, flagC, flag1);

  // fused compaction + filtered bucket scatter
  k_front<<<nblkC + NBLK2, 1024, 0, stream>>>(flagC, flag1, listC, list1, cnt, N, nblkC,
                                              edge_src, edge_dst, E, Etot, epb,
                                              bucketCursor, rec, NB);

  // per-bucket CSR finalize
  k_bcsr<<<NB, 1024, 0, stream>>>(rec, bucketCursor, rowptr, adj, N, NB);

  // layer 1 aggregate -> g (elu'd), grid-strided over list1
  {
    const int gb = 2048;
    k_gat1<<<gb, 256, 0, stream>>>(h1, as1, ad1, rowptr, adj, b1, g, list1, cnt, gb * 4);
  }

  // layer 2 linear (h2 overlays h1), grid-strided over list1
  k_h2<<<1024, 256, 0, stream>>>(g, W2, att_src2, att_dst2, h2, as2, ad2, list1, cnt);

  // layer 2 aggregate -> g2 (overlays g), only for C nodes
  k_gat2<<<(NCTX + 3) / 4, 256, 0, stream>>>(h2, as2, ad2, rowptr, adj, b2, g2, listC, cnt);

  // gather features -> bf16 K-blocked
  k_xmat<<<512, 256, 0, stream>>>(user_idx, context_idx, user_emb, g2, xb);

  // final FC (MFMA, 16 waves x 32 rows, double-buffered 32-col grid-strided tiles)
  const int nfct = (NSRV + 31) / 32;
  const int grid = 512;
  k_fc<<<grid, 1024, 0, stream>>>(xb, fc_w, fc_b, out, NSRV, nfct, grid);
}

// Round 19
// 257.466 us; speedup vs baseline: 1.0879x; 1.0162x over previous
//
#include <hip/hip_runtime.h>
#include <hip/hip_bf16.h>
#include <math.h>

#define NEG_SLOPE 0.2f

// CSR binning parameters (N=100000, E+N~1.7M; requires N < 2^18 and NB <= 256)
#define NPB 512       // nodes per bucket
#define NPB_SH 9
#define SRC_BITS 18
#define LCAP 16384    // LDS adj staging capacity (edges) per bucket
#define BCAP 16384    // fixed per-bucket record capacity (filtered mean ~2.4K)

typedef __attribute__((ext_vector_type(8))) short short8;
typedef __attribute__((ext_vector_type(4))) float f32x4;

__device__ __forceinline__ float leaky(float x) { return x > 0.f ? x : NEG_SLOPE * x; }

__device__ __forceinline__ unsigned short f2bf(float f) {
  unsigned u = __float_as_uint(f);
  unsigned r = (u + 0x7FFFu + ((u >> 16) & 1u)) >> 16;  // RNE
  return (unsigned short)r;
}

// LDS-only barrier: orders ds ops across waves without draining global loads/stores.
#define LGKM_BARRIER()                                   \
  do {                                                   \
    asm volatile("s_waitcnt lgkmcnt(0)" ::: "memory");   \
    __builtin_amdgcn_s_barrier();                        \
  } while (0)

// ---------------- init: zero frontier flags, bucket cursors, counters ----------------
__global__ void k_init(int* __restrict__ cursor, int NB, int* __restrict__ flagC,
                       int* __restrict__ flag1, int* __restrict__ cnt, int N) {
  const int i = blockIdx.x * 256 + threadIdx.x;
  if (i < N) { flagC[i] = 0; flag1[i] = 0; }
  if (i < NB) cursor[i] = i * BCAP;
  if (i < 2) cnt[i] = 0;
}

// ---------------- mark context nodes (plain idempotent stores) ----------------
__global__ void k_markC(const int* __restrict__ ctx, int nctx, int* __restrict__ flagC,
                        int* __restrict__ flag1) {
  const int i = blockIdx.x * 256 + threadIdx.x;
  if (i >= nctx) return;
  const int n = ctx[i];
  flagC[n] = 1;
  flag1[n] = 1;
}

// ---------------- GAT layer 1 linear + fused S1 edge-scan ----------------
// Blocks [0, hb): h1[N,128] = x[N,64] @ W1[64,128] (bf16 out) + attention dots.
// Blocks [hb, hb+nscan): flag1 |= {src[e] : dst[e] in C} (plain stores).
// Both depend only on inputs + flagC (finalized by k_markC).
__global__ void k_h1(const float* __restrict__ x, const float* __restrict__ W1,
                     const float* __restrict__ att_src, const float* __restrict__ att_dst,
                     unsigned short* __restrict__ h1, float* __restrict__ a_s,
                     float* __restrict__ a_d, int N, int hb,
                     const int* __restrict__ src, const int* __restrict__ dst,
                     int E, int Etot, const int* __restrict__ flagC,
                     int* __restrict__ flag1) {
  const int tid = threadIdx.x;
  if ((int)blockIdx.x >= hb) {
    // ---- fused edge scan ----
    const int e = (blockIdx.x - hb) * 256 + tid;
    if (e < Etot) {
      int s, d;
      if (e < E) { s = src[e]; d = dst[e]; } else { s = d = e - E; }
      if (flagC[d]) flag1[s] = 1;
    }
    return;
  }

  __shared__ __align__(16) float W1s[64 * 128];   // 32 KB
  __shared__ __align__(16) float xs[32][64];      // 8 KB
  for (int i = tid; i < 64 * 128; i += 256) W1s[i] = W1[i];
  const int node0 = blockIdx.x * 32;
  for (int i = tid; i < 512; i += 256) {
    const int nn = node0 + (i >> 4);
    if (nn < N) ((float4*)xs)[i] = *(const float4*)(x + (size_t)nn * 64 + (i & 15) * 4);
  }
  const int ln  = tid >> 7;   // node slot 0/1
  const int col = tid & 127;  // output channel
  const int head = col >> 6;
  const int c = col & 63;
  const float as_w = att_src[head * 64 + c];
  const float ad_w = att_dst[head * 64 + c];
  __syncthreads();  // W1s + xs ready
  float wreg[64];
#pragma unroll
  for (int cc = 0; cc < 64; ++cc) wreg[cc] = W1s[cc * 128 + col];

  for (int it = 0; it < 16; ++it) {
    const int slot = it * 2 + ln;
    const int n = node0 + slot;
    if (n >= N) continue;
    float acc = 0.f;
#pragma unroll
    for (int q = 0; q < 16; ++q) {
      const float4 xv = *(const float4*)&xs[slot][q * 4];
      acc = fmaf(xv.x, wreg[q * 4 + 0], acc);
      acc = fmaf(xv.y, wreg[q * 4 + 1], acc);
      acc = fmaf(xv.z, wreg[q * 4 + 2], acc);
      acc = fmaf(xv.w, wreg[q * 4 + 3], acc);
    }
    h1[(size_t)n * 128 + col] = f2bf(acc);
    float vs = acc * as_w;
    float vd = acc * ad_w;
#pragma unroll
    for (int off = 32; off > 0; off >>= 1) {
      vs += __shfl_down(vs, off, 64);
      vd += __shfl_down(vd, off, 64);
    }
    if (c == 0) { a_s[n * 2 + head] = vs; a_d[n * 2 + head] = vd; }
  }
}

// ---------------- fused: flag compaction + filtered bucket scatter ----------------
__global__ __launch_bounds__(1024) void k_front(
    const int* __restrict__ flagC, const int* __restrict__ flag1,
    int* __restrict__ listC, int* __restrict__ list1, int* __restrict__ cnt,
    int N, int nblkC,
    const int* __restrict__ src, const int* __restrict__ dst, int E, int Etot,
    int epb, int* __restrict__ cursor, unsigned* __restrict__ rec, int NB) {
  __shared__ int hist[256];
  __shared__ int cur[256];
  const int tid = threadIdx.x;

  if ((int)blockIdx.x < nblkC) {
    // ---- compaction ----
    const int i = blockIdx.x * 1024 + tid;
    if (tid == 0) { hist[0] = 0; hist[1] = 0; }
    __syncthreads();
    int pc = -1, p1 = -1;
    if (i < N) {
      if (flagC[i]) pc = atomicAdd(&hist[0], 1);
      if (flag1[i]) p1 = atomicAdd(&hist[1], 1);
    }
    __syncthreads();
    if (tid == 0) {
      cur[0] = hist[0] ? atomicAdd(&cnt[0], hist[0]) : 0;
      cur[1] = hist[1] ? atomicAdd(&cnt[1], hist[1]) : 0;
    }
    __syncthreads();
    if (pc >= 0) listC[cur[0] + pc] = i;
    if (p1 >= 0) list1[cur[1] + p1] = i;
    return;
  }

  // ---- filtered bucket scatter ----
  const int bb = blockIdx.x - nblkC;
  if (tid < 256) hist[tid] = 0;
  __syncthreads();
  const int e0 = bb * epb;
  const int e1 = min(e0 + epb, Etot);
  for (int e = e0 + tid; e < e1; e += 1024) {
    const int d = (e < E) ? dst[e] : (e - E);
    if (flag1[d]) atomicAdd(&hist[d >> NPB_SH], 1);
  }
  __syncthreads();
  if (tid < NB) {
    const int c = hist[tid];
    cur[tid] = c ? atomicAdd(&cursor[tid], c) : 0;
  }
  __syncthreads();
  for (int e = e0 + tid; e < e1; e += 1024) {
    int sv, d;
    if (e < E) { sv = src[e]; d = dst[e]; } else { sv = d = e - E; }
    if (!flag1[d]) continue;
    const int b = d >> NPB_SH;
    const int p = atomicAdd(&cur[b], 1);
    rec[p] = (unsigned)sv | ((unsigned)(d & (NPB - 1)) << SRC_BITS);
  }
}

// one block per bucket: recompute bucket prefix from cursor deltas, then local
// degree count, scan, LDS scatter, coalesced copy out.
__global__ __launch_bounds__(1024) void k_bcsr(const unsigned* __restrict__ rec,
                                               const int* __restrict__ cursor,
                                               int* __restrict__ rowptr, int* __restrict__ adj,
                                               int N, int NB) {
  __shared__ int ldeg[NPB];
  __shared__ int s[NPB];
  __shared__ int ladj[LCAP];
  __shared__ int o0s, cnts;
  const int b = blockIdx.x;
  const int tid = threadIdx.x;

  if (tid < 256) s[tid] = (tid < NB) ? (cursor[tid] - tid * BCAP) : 0;
  __syncthreads();
  for (int off = 1; off < 256; off <<= 1) {
    int t = 0;
    if (tid < 256 && tid >= off) t = s[tid - off];
    __syncthreads();
    if (tid < 256) s[tid] += t;
    __syncthreads();
  }
  if (tid == 0) {
    const int cb = cursor[b] - b * BCAP;
    o0s = s[b] - cb;
    cnts = cb;
    if (b == 0) rowptr[N] = s[NB - 1];
  }
  __syncthreads();
  const int o0 = o0s;
  const int cnt = cnts;
  const int r0 = b * BCAP;

  if (tid < NPB) ldeg[tid] = 0;
  __syncthreads();
  for (int i = tid; i < cnt; i += 1024)
    atomicAdd(&ldeg[rec[r0 + i] >> SRC_BITS], 1);
  __syncthreads();
  int v = 0;
  if (tid < NPB) { v = ldeg[tid]; s[tid] = v; }
  __syncthreads();
  for (int off = 1; off < NPB; off <<= 1) {
    int t = 0;
    if (tid < NPB && tid >= off) t = s[tid - off];
    __syncthreads();
    if (tid < NPB) s[tid] += t;
    __syncthreads();
  }
  if (tid < NPB) {
    const int excl = s[tid] - v;
    const int node = b * NPB + tid;
    if (node < N) rowptr[node] = o0 + excl;
    ldeg[tid] = excl;  // reuse as scatter cursor
  }
  __syncthreads();
  if (cnt <= LCAP) {
    for (int i = tid; i < cnt; i += 1024) {
      const unsigned r = rec[r0 + i];
      const int p = atomicAdd(&ldeg[r >> SRC_BITS], 1);
      ladj[p] = (int)(r & ((1u << SRC_BITS) - 1));
    }
    __syncthreads();
    for (int i = tid; i < cnt; i += 1024) adj[o0 + i] = ladj[i];
  } else {  // safety fallback (never expected)
    for (int i = tid; i < cnt; i += 1024) {
      const unsigned r = rec[r0 + i];
      const int p = atomicAdd(&ldeg[r >> SRC_BITS], 1);
      adj[o0 + p] = (int)(r & ((1u << SRC_BITS) - 1));
    }
  }
}

// ---------------- GAT layer 1 aggregate over list1 (grid-strided, x4 unroll) -------
__global__ void k_gat1(const unsigned short* __restrict__ h1, const float* __restrict__ as1,
                       const float* __restrict__ ad1, const int* __restrict__ rowptr,
                       const int* __restrict__ adj, const float* __restrict__ b1,
                       float* __restrict__ g, const int* __restrict__ list1,
                       const int* __restrict__ cnt, int gspan) {
  const int w = threadIdx.x >> 6;
  const int l = threadIdx.x & 63;
  const int half = l >> 5;
  const int q = l & 31;       // channels 4q..4q+3
  const int head = q >> 4;
  const int cnt1 = cnt[1];
  for (int idx = blockIdx.x * 4 + w; idx < cnt1; idx += gspan) {
    const int n = list1[idx];
    const float adh = ad1[n * 2 + head];
    float a0 = 0.f, a1 = 0.f, a2 = 0.f, a3 = 0.f, dsum = 0.f;
    const int kb = rowptr[n], ke = rowptr[n + 1];
    const int kend = ke - 1;
    for (int k = kb + half; k < ke; k += 8) {
      const int e1 = k + 2, e2 = k + 4, e3 = k + 6;
      const int s0 = adj[k];
      const int s1 = adj[min(e1, kend)];
      const int s2 = adj[min(e2, kend)];
      const int s3 = adj[min(e3, kend)];
      const float x0 = as1[s0 * 2 + head] + adh;
      const float x1 = as1[s1 * 2 + head] + adh;
      const float x2 = as1[s2 * 2 + head] + adh;
      const float x3 = as1[s3 * 2 + head] + adh;
      const uint2 u0 = *(const uint2*)(h1 + (size_t)s0 * 128 + 4 * q);
      const uint2 u1 = *(const uint2*)(h1 + (size_t)s1 * 128 + 4 * q);
      const uint2 u2 = *(const uint2*)(h1 + (size_t)s2 * 128 + 4 * q);
      const uint2 u3 = *(const uint2*)(h1 + (size_t)s3 * 128 + 4 * q);
      const float w0 = __expf(leaky(x0));
      const float w1 = (e1 < ke) ? __expf(leaky(x1)) : 0.f;
      const float w2 = (e2 < ke) ? __expf(leaky(x2)) : 0.f;
      const float w3 = (e3 < ke) ? __expf(leaky(x3)) : 0.f;
      dsum += (w0 + w1) + (w2 + w3);
      a0 = fmaf(w0, __uint_as_float(u0.x << 16), a0);
      a1 = fmaf(w0, __uint_as_float(u0.x & 0xFFFF0000u), a1);
      a2 = fmaf(w0, __uint_as_float(u0.y << 16), a2);
      a3 = fmaf(w0, __uint_as_float(u0.y & 0xFFFF0000u), a3);
      a0 = fmaf(w1, __uint_as_float(u1.x << 16), a0);
      a1 = fmaf(w1, __uint_as_float(u1.x & 0xFFFF0000u), a1);
      a2 = fmaf(w1, __uint_as_float(u1.y << 16), a2);
      a3 = fmaf(w1, __uint_as_float(u1.y & 0xFFFF0000u), a3);
      a0 = fmaf(w2, __uint_as_float(u2.x << 16), a0);
      a1 = fmaf(w2, __uint_as_float(u2.x & 0xFFFF0000u), a1);
      a2 = fmaf(w2, __uint_as_float(u2.y << 16), a2);
      a3 = fmaf(w2, __uint_as_float(u2.y & 0xFFFF0000u), a3);
      a0 = fmaf(w3, __uint_as_float(u3.x << 16), a0);
      a1 = fmaf(w3, __uint_as_float(u3.x & 0xFFFF0000u), a1);
      a2 = fmaf(w3, __uint_as_float(u3.y << 16), a2);
      a3 = fmaf(w3, __uint_as_float(u3.y & 0xFFFF0000u), a3);
    }
    a0 += __shfl_xor(a0, 32, 64);
    a1 += __shfl_xor(a1, 32, 64);
    a2 += __shfl_xor(a2, 32, 64);
    a3 += __shfl_xor(a3, 32, 64);
    dsum += __shfl_xor(dsum, 32, 64);
    if (half == 0) {
      const float inv = 1.f / (dsum + 1e-16f);
      const float4 bv = *(const float4*)(b1 + 4 * q);
      float g0 = fmaf(a0, inv, bv.x);
      float g1 = fmaf(a1, inv, bv.y);
      float g2v = fmaf(a2, inv, bv.z);
      float g3 = fmaf(a3, inv, bv.w);
      g0 = g0 > 0.f ? g0 : expm1f(g0);
      g1 = g1 > 0.f ? g1 : expm1f(g1);
      g2v = g2v > 0.f ? g2v : expm1f(g2v);
      g3 = g3 > 0.f ? g3 : expm1f(g3);
      *(float4*)(g + (size_t)n * 128 + 4 * q) = make_float4(g0, g1, g2v, g3);
    }
  }
}

// ---------------- GAT layer 2 linear over list1 (grid-strided): h2 = g @ W2 --------
__global__ void k_h2(const float* __restrict__ g, const float* __restrict__ W2,
                     const float* __restrict__ att_s, const float* __restrict__ att_d,
                     unsigned short* __restrict__ h2, float* __restrict__ a_s,
                     float* __restrict__ a_d, const int* __restrict__ list1,
                     const int* __restrict__ cnt) {
  const int cnt1 = cnt[1];
  __shared__ __align__(16) float W2s[128 * 64];
  __shared__ __align__(16) float gs[2][128];
  __shared__ float part[2][64];
  for (int i = threadIdx.x; i < 128 * 64; i += 256) W2s[i] = W2[i];
  const int col = threadIdx.x & 63;
  const int kh  = (threadIdx.x >> 6) & 1;
  const int ln  = threadIdx.x >> 7;
  const float as_w = att_s[col], ad_w = att_d[col];
  __syncthreads();
  float wreg[64];
#pragma unroll
  for (int cc = 0; cc < 64; ++cc) wreg[cc] = W2s[(kh * 64 + cc) * 64 + col];

  for (int base0 = blockIdx.x * 32; base0 < cnt1; base0 += gridDim.x * 32) {
    for (int it = 0; it < 16; ++it) {
      const int sbase = base0 + it * 2;
      __syncthreads();
      {
        const int slot = sbase + (threadIdx.x >> 7);
        if (slot < cnt1) {
          const int nn = list1[slot];
          gs[threadIdx.x >> 7][threadIdx.x & 127] = g[(size_t)nn * 128 + (threadIdx.x & 127)];
        }
      }
      __syncthreads();
      const int slot = sbase + ln;
      const int n = (slot < cnt1) ? list1[slot] : -1;
      float acc = 0.f;
      if (n >= 0) {
#pragma unroll
        for (int q = 0; q < 16; ++q) {
          const float4 gv = *(const float4*)&gs[ln][kh * 64 + q * 4];
          acc = fmaf(gv.x, wreg[q * 4 + 0], acc);
          acc = fmaf(gv.y, wreg[q * 4 + 1], acc);
          acc = fmaf(gv.z, wreg[q * 4 + 2], acc);
          acc = fmaf(gv.w, wreg[q * 4 + 3], acc);
        }
      }
      if (kh == 1) part[ln][col] = acc;
      __syncthreads();
      if (kh == 0 && n >= 0) {
        acc += part[ln][col];
        h2[(size_t)n * 64 + col] = f2bf(acc);
        float vs = acc * as_w, vd = acc * ad_w;
#pragma unroll
        for (int off = 32; off > 0; off >>= 1) {
          vs += __shfl_down(vs, off, 64);
          vd += __shfl_down(vd, off, 64);
        }
        if (col == 0) { a_s[n] = vs; a_d[n] = vd; }
      }
    }
  }
}

// ---------------- GAT layer 2 aggregate over listC (x4 unroll) ----------------
__global__ void k_gat2(const unsigned short* __restrict__ h2, const float* __restrict__ as2,
                       const float* __restrict__ ad2, const int* __restrict__ rowptr,
                       const int* __restrict__ adj, const float* __restrict__ b2,
                       float* __restrict__ g2, const int* __restrict__ listC,
                       const int* __restrict__ cnt) {
  const int w = threadIdx.x >> 6;
  const int l = threadIdx.x & 63;
  const int idx = blockIdx.x * 4 + w;
  if (idx >= cnt[0]) return;
  const int n = listC[idx];
  const int half = l >> 5;
  const int q = l & 31;       // channels 2q, 2q+1
  const float adh = ad2[n];
  float a0 = 0.f, a1 = 0.f, dsum = 0.f;
  const int kb = rowptr[n], ke = rowptr[n + 1];
  const int kend = ke - 1;
  for (int k = kb + half; k < ke; k += 8) {
    const int e1 = k + 2, e2 = k + 4, e3 = k + 6;
    const int s0 = adj[k];
    const int s1 = adj[min(e1, kend)];
    const int s2 = adj[min(e2, kend)];
    const int s3 = adj[min(e3, kend)];
    const float x0 = as2[s0] + adh;
    const float x1 = as2[s1] + adh;
    const float x2 = as2[s2] + adh;
    const float x3 = as2[s3] + adh;
    const unsigned u0 = *(const unsigned*)(h2 + (size_t)s0 * 64 + 2 * q);
    const unsigned u1 = *(const unsigned*)(h2 + (size_t)s1 * 64 + 2 * q);
    const unsigned u2 = *(const unsigned*)(h2 + (size_t)s2 * 64 + 2 * q);
    const unsigned u3 = *(const unsigned*)(h2 + (size_t)s3 * 64 + 2 * q);
    const float w0 = __expf(leaky(x0));
    const float w1 = (e1 < ke) ? __expf(leaky(x1)) : 0.f;
    const float w2 = (e2 < ke) ? __expf(leaky(x2)) : 0.f;
    const float w3 = (e3 < ke) ? __expf(leaky(x3)) : 0.f;
    dsum += (w0 + w1) + (w2 + w3);
    a0 = fmaf(w0, __uint_as_float(u0 << 16), a0);
    a1 = fmaf(w0, __uint_as_float(u0 & 0xFFFF0000u), a1);
    a0 = fmaf(w1, __uint_as_float(u1 << 16), a0);
    a1 = fmaf(w1, __uint_as_float(u1 & 0xFFFF0000u), a1);
    a0 = fmaf(w2, __uint_as_float(u2 << 16), a0);
    a1 = fmaf(w2, __uint_as_float(u2 & 0xFFFF0000u), a1);
    a0 = fmaf(w3, __uint_as_float(u3 << 16), a0);
    a1 = fmaf(w3, __uint_as_float(u3 & 0xFFFF0000u), a1);
  }
  a0 += __shfl_xor(a0, 32, 64);
  a1 += __shfl_xor(a1, 32, 64);
  dsum += __shfl_xor(dsum, 32, 64);
  if (half == 0) {
    const float inv = 1.f / (dsum + 1e-16f);
    const float2 bv = *(const float2*)(b2 + 2 * q);
    ((float2*)g2)[(size_t)n * 32 + q] =
        make_float2(fmaf(a0, inv, bv.x), fmaf(a1, inv, bv.y));
  }
}

// ---------------- build x matrix, bf16, K-blocked: xb[k/32][512][32] ----------------
__global__ void k_xmat(const int* __restrict__ user_idx, const int* __restrict__ ctx_idx,
                       const float* __restrict__ user_emb, const float* __restrict__ g2,
                       unsigned short* __restrict__ xb) {
  const int b = blockIdx.x;
  const int k = threadIdx.x;  // 0..255
  float v;
  if (k < 64) {
    v = user_emb[(size_t)user_idx[b] * 64 + k];
  } else {
    const int c = (k - 64) >> 6;
    v = g2[(size_t)ctx_idx[b * 3 + c] * 64 + (k & 63)];
  }
  xb[(size_t)(k >> 5) * (512 * 32) + b * 32 + (k & 31)] = f2bf(v);
}

// ---------------- final FC via MFMA: 1024 threads, 16 waves x 32 rows -------------
__global__ __launch_bounds__(1024) void k_fc(const unsigned short* __restrict__ xb,
                                             const float* __restrict__ fc_w,
                                             const float* __restrict__ fc_b,
                                             float* __restrict__ out, int NSRV,
                                             int ntiles, int gstride) {
  __shared__ __align__(16) unsigned short Blds[2][32 * 264];  // 33 KB

  const int tid = threadIdx.x;
  const int w = tid >> 6;        // wave 0..15, owns rows [32w, 32w+32)
  const int lane = tid & 63;
  const int l15 = lane & 15;
  const int kg = lane >> 4;

  if (blockIdx.x >= (unsigned)ntiles) return;

  // persistent A fragments (MFMA B operand after the swap): 2 mf x 8 ks
  short8 afr[2][8];
#pragma unroll
  for (int mf = 0; mf < 2; ++mf) {
    const int row = w * 32 + mf * 16 + l15;
#pragma unroll
    for (int ks = 0; ks < 8; ++ks) {
      afr[mf][ks] = *(const short8*)(xb + (size_t)ks * 16384 + row * 32 + kg * 8);
    }
  }

  const int sc  = tid & 31;         // stage: col in tile
  const int sk0 = (tid >> 5) * 8;   // stage: contiguous k-chunk base (0,8,..,248)

  float v[8];
  auto loadv = [&](int t) {
    const int cg = t * 32 + sc;
    const bool okc = cg < NSRV;
#pragma unroll
    for (int i = 0; i < 8; ++i)
      v[i] = okc ? __builtin_nontemporal_load(fc_w + (size_t)(sk0 + i) * NSRV + cg) : 0.f;
  };
  auto writev = [&](int buf) {
    short8 lo;
#pragma unroll
    for (int i = 0; i < 8; ++i) lo[i] = (short)f2bf(v[i]);
    *(short8*)&Blds[buf][sc * 264 + sk0] = lo;
  };

  // prologue: tile t0 staged, loads for t0+gs in flight
  loadv(blockIdx.x);
  writev(0);
  if (blockIdx.x + gstride < ntiles) loadv(blockIdx.x + gstride);
  LGKM_BARRIER();

  int cur = 0;
  for (int t = blockIdx.x; t < ntiles; t += gstride) {
    if (t + gstride < ntiles) writev(cur ^ 1);   // consumes loads issued a tile ago
    if (t + 2 * gstride < ntiles) loadv(t + 2 * gstride);
    const int j0 = t * 32;
#pragma unroll
    for (int nf = 0; nf < 2; ++nf) {
      short8 bfr[8];
#pragma unroll
      for (int ks = 0; ks < 8; ++ks)
        bfr[ks] = *(const short8*)&Blds[cur][(nf * 16 + l15) * 264 + ks * 32 + kg * 8];
      f32x4 acc[2];
#pragma unroll
      for (int mf = 0; mf < 2; ++mf) acc[mf] = (f32x4){0.f, 0.f, 0.f, 0.f};
#pragma unroll
      for (int ks = 0; ks < 8; ++ks)
#pragma unroll
        for (int mf = 0; mf < 2; ++mf)
          acc[mf] = __builtin_amdgcn_mfma_f32_16x16x32_bf16(bfr[ks], afr[mf][ks], acc[mf], 0, 0, 0);
      const int jc = j0 + nf * 16 + kg * 4;
      if (j0 + 32 <= NSRV) {
        const float4 bias = *(const float4*)(fc_b + jc);
#pragma unroll
        for (int mf = 0; mf < 2; ++mf) {
          const int row = w * 32 + mf * 16 + l15;
          f32x4 o;
          o[0] = acc[mf][0] + bias.x;
          o[1] = acc[mf][1] + bias.y;
          o[2] = acc[mf][2] + bias.z;
          o[3] = acc[mf][3] + bias.w;
          __builtin_nontemporal_store(o, (f32x4*)(out + (size_t)row * NSRV + jc));
        }
      } else {
#pragma unroll
        for (int mf = 0; mf < 2; ++mf) {
          const int row = w * 32 + mf * 16 + l15;
#pragma unroll
          for (int r = 0; r < 4; ++r) {
            const int j = jc + r;
            if (j < NSRV) out[(size_t)row * NSRV + j] = acc[mf][r] + fc_b[j];
          }
        }
      }
    }
    LGKM_BARRIER();
    cur ^= 1;
  }
}

// =====================================================================
extern "C" void kernel_launch(void* const* d_in, const int* in_sizes, int n_in,
                              void* d_out, int out_size, void* d_ws, size_t ws_size,
                              hipStream_t stream) {
  const int* user_idx    = (const int*)d_in[0];
  const int* context_idx = (const int*)d_in[1];
  const int* edge_index  = (const int*)d_in[2];
  const float* user_emb  = (const float*)d_in[3];
  const float* service_emb = (const float*)d_in[4];
  const float* W1        = (const float*)d_in[5];
  const float* att_src1  = (const float*)d_in[6];
  const float* att_dst1  = (const float*)d_in[7];
  const float* b1        = (const float*)d_in[8];
  const float* W2        = (const float*)d_in[9];
  const float* att_src2  = (const float*)d_in[10];
  const float* att_dst2  = (const float*)d_in[11];
  const float* b2        = (const float*)d_in[12];
  const float* fc_w      = (const float*)d_in[13];
  const float* fc_b      = (const float*)d_in[14];
  float* out = (float*)d_out;

  const int B    = in_sizes[0];
  const int E    = in_sizes[2] / 2;
  const int N    = in_sizes[4] / 64;
  const int NSRV = in_sizes[14];
  const int Etot = E + N;
  const int NCTX = in_sizes[1];  // B*CTX
  (void)B;

  const int* edge_src = edge_index;
  const int* edge_dst = edge_index + E;

  // ---- workspace layout ----
  char* ws = (char*)d_ws;
  size_t off = 0;
  auto alloc = [&](size_t bytes) {
    void* p = ws + off;
    off = (off + bytes + 255) & ~(size_t)255;
    return p;
  };
  const int NB = (N + NPB - 1) >> NPB_SH;   // 196 for N=100000 (requires <=256)
  unsigned short* h1 = (unsigned short*)alloc((size_t)N * 128 * 2);  // reused as h2
  float* g      = (float*)alloc((size_t)N * 128 * 4);                // reused as g2
  float* as1    = (float*)alloc((size_t)N * 2 * 4);
  float* ad1    = (float*)alloc((size_t)N * 2 * 4);
  float* as2    = (float*)alloc((size_t)N * 4);
  float* ad2    = (float*)alloc((size_t)N * 4);
  int*   rowptr = (int*)alloc((size_t)(N + 1) * 4);
  int*   adj    = (int*)alloc((size_t)Etot * 4);
  unsigned* rec = (unsigned*)alloc((size_t)NB * BCAP * 4);
  int* bucketCursor = (int*)alloc(256 * 4);
  int* flagC  = (int*)alloc((size_t)N * 4);
  int* flag1  = (int*)alloc((size_t)N * 4);
  int* listC  = (int*)alloc((size_t)NCTX * 4);
  int* list1  = (int*)alloc((size_t)N * 4);
  int* cnt    = (int*)alloc(2 * 4);
  unsigned short* xb = (unsigned short*)alloc((size_t)512 * 256 * 2);
  unsigned short* h2 = h1;
  float* g2 = g;
  (void)ws_size;

  const int NBLK2 = 256;
  const int epb = (Etot + NBLK2 - 1) / NBLK2;
  const int nblk_N = (N + 255) / 256;
  const int nblk_E = (Etot + 255) / 256;
  const int nblkC = (N + 1023) / 1024;   // compaction blocks (1024 thr)
  const int hb = (N + 31) / 32;          // h1 compute blocks

  // init flags/cursors/counters
  k_init<<<nblk_N, 256, 0, stream>>>(bucketCursor, NB, flagC, flag1, cnt, N);

  // mark context nodes
  k_markC<<<(NCTX + 255) / 256, 256, 0, stream>>>(context_idx, NCTX, flagC, flag1);

  // GAT layer 1 linear + fused S1 edge-scan (independent work, one dispatch)
  k_h1<<<hb + nblk_E, 256, 0, stream>>>(service_emb, W1, att_src1, att_dst1, h1, as1, ad1, N,
                                        hb, edge_src, edge_dst, E, Etot, flagC, flag1);

  // fused compaction + filtered bucket scatter
  k_front<<<nblkC + NBLK2, 1024, 0, stream>>>(flagC, flag1, listC, list1, cnt, N, nblkC,
                                              edge_src, edge_dst, E, Etot, epb,
                                              bucketCursor, rec, NB);

  // per-bucket CSR finalize
  k_bcsr<<<NB, 1024, 0, stream>>>(rec, bucketCursor, rowptr, adj, N, NB);

  // layer 1 aggregate -> g (elu'd), grid-strided over list1
  {
    const int gb = 2048;
    k_gat1<<<gb, 256, 0, stream>>>(h1, as1, ad1, rowptr, adj, b1, g, list1, cnt, gb * 4);
  }

  // layer 2 linear (h2 overlays h1), grid-strided over list1
  k_h2<<<1024, 256, 0, stream>>>(g, W2, att_src2, att_dst2, h2, as2, ad2, list1, cnt);

  // layer 2 aggregate -> g2 (overlays g), only for C nodes
  k_gat2<<<(NCTX + 3) / 4, 256, 0, stream>>>(h2, as2, ad2, rowptr, adj, b2, g2, listC, cnt);

  // gather features -> bf16 K-blocked
  k_xmat<<<512, 256, 0, stream>>>(user_idx, context_idx, user_emb, g2, xb);

  // final FC (MFMA, 16 waves x 32 rows, double-buffered 32-col grid-strided tiles)
  const int nfct = (NSRV + 31) / 32;
  const int grid = 512;
  k_fc<<<grid, 1024, 0, stream>>>(xb, fc_w, fc_b, out, NSRV, nfct, grid);
}